// Round 9
// baseline (210.785 us; speedup 1.0000x reference)
//
#include <hip/hip_runtime.h>
#include <math.h>

// Problem constants (match reference)
#define FIN   128
#define HC1   128   // H*C for layer 1
#define NCLS  16
#define NEG_SLOPE 0.2f

typedef __attribute__((ext_vector_type(8))) short bf16x8;
typedef __attribute__((ext_vector_type(4))) float f32x4;

__device__ __forceinline__ unsigned short f2bf_rne(float f) {
    unsigned int u = __float_as_uint(f);
    unsigned int r = u + 0x7FFFu + ((u >> 16) & 1u);
    return (unsigned short)(r >> 16);
}
__device__ __forceinline__ float bf2f(unsigned short h) {
    return __uint_as_float(((unsigned int)h) << 16);
}
__device__ __forceinline__ float bflo(unsigned int u) { return __uint_as_float(u << 16); }
__device__ __forceinline__ float bfhi(unsigned int u) { return __uint_as_float(u & 0xFFFF0000u); }

// ---------------------------------------------------------------------------
// CSR build via two-level bucket sort (bucket = dst>>8).
// Memset-free + global-atomic-free: per-block histogram matrix blockhist,
// rewritten in-place by bscan into per-(block,bucket) bases.
// Self-loops are NOT in the CSR; scores/gather handle them analytically.
// ---------------------------------------------------------------------------
#define EPB 4096   // edges per block in bcnt/binA

__global__ __launch_bounds__(256)
void bcnt_kernel(const int* __restrict__ ei, int* __restrict__ blockhist,
                 int E, int NB) {
    __shared__ int h[256];
    int tid = threadIdx.x;
    h[tid] = 0;
    __syncthreads();
    int base = blockIdx.x * EPB;
#pragma unroll
    for (int j = 0; j < EPB / 256; ++j) {
        int e = base + j * 256 + tid;
        if (e < E) atomicAdd(&h[ei[E + e] >> 8], 1);
    }
    __syncthreads();
    if (tid < NB) blockhist[blockIdx.x * NB + tid] = h[tid];
}

// One block. Column-sum blockhist -> bucket totals -> scan -> bucket_base;
// then rewrite blockhist[b][t] into running exclusive base per bucket.
__global__ __launch_bounds__(256)
void bscan_kernel(int* __restrict__ blockhist, int* __restrict__ bucket_base,
                  int EB, int NB) {
    __shared__ int lds[256];
    int t = threadIdx.x;
    int tot = 0;
    if (t < NB)
        for (int b = 0; b < EB; ++b) tot += blockhist[b * NB + t];
    lds[t] = (t < NB) ? tot : 0;
    __syncthreads();
    for (int off = 1; off < 256; off <<= 1) {
        int u = (t >= off) ? lds[t - off] : 0;
        __syncthreads();
        lds[t] += u;
        __syncthreads();
    }
    int excl = lds[t] - ((t < NB) ? tot : 0);
    if (t < NB) bucket_base[t] = excl;
    if (t == 255) bucket_base[NB] = lds[255];   // == E
    if (t < NB) {
        int run = excl;
        for (int b = 0; b < EB; ++b) {
            int c = blockhist[b * NB + t];
            blockhist[b * NB + t] = run;
            run += c;
        }
    }
}

__global__ __launch_bounds__(256)
void binA_kernel(const int* __restrict__ ei, const int* __restrict__ blockhist,
                 int2* __restrict__ tmp, int E, int NB) {
    __shared__ int h[256];    // local cursors
    __shared__ int bb[256];   // this block's global base per bucket
    int tid = threadIdx.x;
    h[tid] = 0;
    if (tid < NB) bb[tid] = blockhist[blockIdx.x * NB + tid];
    __syncthreads();
    int base = blockIdx.x * EPB;
#pragma unroll
    for (int j = 0; j < EPB / 256; ++j) {
        int e = base + j * 256 + tid;
        if (e < E) {
            int s = ei[e], d = ei[E + e];
            int b = d >> 8;
            int r = atomicAdd(&h[b], 1);
            tmp[bb[b] + r] = make_int2(s, d);
        }
    }
}

// One block per bucket: sorts its bucket by node, writes csr densely and
// emits eoffs (global CSR offsets) directly.
__global__ __launch_bounds__(256)
void binB_kernel(const int2* __restrict__ tmp, const int* __restrict__ bucket_base,
                 int* __restrict__ csr, int* __restrict__ eoffs, int E, int N) {
    __shared__ int cnt[256];
    __shared__ int lds[256];
    __shared__ int cur[256];
    int b = blockIdx.x, t = threadIdx.x;
    int lo = bucket_base[b], hi = bucket_base[b + 1];
    cnt[t] = 0;
    __syncthreads();
    for (int i = lo + t; i < hi; i += 256)
        atomicAdd(&cnt[tmp[i].y & 255], 1);
    __syncthreads();
    int v = cnt[t];
    lds[t] = v;
    __syncthreads();
    for (int off = 1; off < 256; off <<= 1) {
        int u = (t >= off) ? lds[t - off] : 0;
        __syncthreads();
        lds[t] += u;
        __syncthreads();
    }
    int excl = lds[t] - v;
    int node = b * 256 + t;
    if (node < N) eoffs[node] = lo + excl;
    if (b == 0 && t == 0) eoffs[N] = E;
    cur[t] = lo + excl;
    __syncthreads();
    for (int i = lo + t; i < hi; i += 256) {
        int2 e = tmp[i];
        int p = atomicAdd(&cur[e.y & 255], 1);
        csr[p] = e.x;
    }
}

// ---------------------------------------------------------------------------
// Layer 1 GEMM via split-bf16 MFMA: h1 = x @ W1, ~fp32 accuracy.
// h1 stored bf16; alpha scalars from full fp32 accumulator.
// ---------------------------------------------------------------------------
__global__ __launch_bounds__(256)
void gemm1_mfma(const float* __restrict__ x, const float* __restrict__ W,
                const float* __restrict__ a_src, const float* __restrict__ a_dst,
                unsigned short* __restrict__ h1b, float* __restrict__ as1,
                float* __restrict__ ad1, int N) {
    __shared__ unsigned short whi[FIN * HC1];   // 32 KB, fragment-ordered
    __shared__ unsigned short wlo[FIN * HC1];   // 32 KB
    int tid = threadIdx.x;

#pragma unroll
    for (int i = 0; i < 64; ++i) {
        int idx = tid + i * 256;            // 0..16383, coalesced
        int k = idx >> 7, c = idx & 127;
        float v = W[idx];
        unsigned short hb = f2bf_rne(v);
        unsigned short lb = f2bf_rne(v - bf2f(hb));
        int kb = k >> 5, kk = k & 31;
        int g = kk >> 3, j = kk & 7;
        int ct = c >> 4, li = c & 15;
        int off = ((kb * 8 + ct) * 64 + g * 16 + li) * 8 + j;
        whi[off] = hb;
        wlo[off] = lb;
    }

    int wid = tid >> 6, lane = tid & 63;
    int li = lane & 15, g = lane >> 4;
    int rowbase = blockIdx.x * 64 + wid * 16;

    int arow = rowbase + li;
    if (arow >= N) arow = N - 1;            // clamp; invalid rows never stored
    const float* xp = x + (long)arow * FIN + g * 8;
    bf16x8 Ahi[4], Alo[4];
#pragma unroll
    for (int kb = 0; kb < 4; ++kb) {
        float4 v0 = *reinterpret_cast<const float4*>(xp + kb * 32);
        float4 v1 = *reinterpret_cast<const float4*>(xp + kb * 32 + 4);
        float vs0 = v0.x, vs1 = v0.y, vs2 = v0.z, vs3 = v0.w;
        float vs4 = v1.x, vs5 = v1.y, vs6 = v1.z, vs7 = v1.w;
        bf16x8 h8, l8;
        unsigned short hb;
        hb = f2bf_rne(vs0); h8[0] = (short)hb; l8[0] = (short)f2bf_rne(vs0 - bf2f(hb));
        hb = f2bf_rne(vs1); h8[1] = (short)hb; l8[1] = (short)f2bf_rne(vs1 - bf2f(hb));
        hb = f2bf_rne(vs2); h8[2] = (short)hb; l8[2] = (short)f2bf_rne(vs2 - bf2f(hb));
        hb = f2bf_rne(vs3); h8[3] = (short)hb; l8[3] = (short)f2bf_rne(vs3 - bf2f(hb));
        hb = f2bf_rne(vs4); h8[4] = (short)hb; l8[4] = (short)f2bf_rne(vs4 - bf2f(hb));
        hb = f2bf_rne(vs5); h8[5] = (short)hb; l8[5] = (short)f2bf_rne(vs5 - bf2f(hb));
        hb = f2bf_rne(vs6); h8[6] = (short)hb; l8[6] = (short)f2bf_rne(vs6 - bf2f(hb));
        hb = f2bf_rne(vs7); h8[7] = (short)hb; l8[7] = (short)f2bf_rne(vs7 - bf2f(hb));
        Ahi[kb] = h8; Alo[kb] = l8;
    }

    float asr[8], adr[8];
#pragma unroll
    for (int ct = 0; ct < 8; ++ct) {
        asr[ct] = a_src[ct * 16 + li];
        adr[ct] = a_dst[ct * 16 + li];
    }

    __syncthreads();

    f32x4 acc[8];
#pragma unroll
    for (int ct = 0; ct < 8; ++ct) acc[ct] = (f32x4){0.f, 0.f, 0.f, 0.f};

#pragma unroll
    for (int kb = 0; kb < 4; ++kb) {
#pragma unroll
        for (int ct = 0; ct < 8; ++ct) {
            bf16x8 bh = *reinterpret_cast<const bf16x8*>(&whi[((kb * 8 + ct) * 64 + lane) * 8]);
            bf16x8 bl = *reinterpret_cast<const bf16x8*>(&wlo[((kb * 8 + ct) * 64 + lane) * 8]);
            acc[ct] = __builtin_amdgcn_mfma_f32_16x16x32_bf16(Alo[kb], bh, acc[ct], 0, 0, 0);
            acc[ct] = __builtin_amdgcn_mfma_f32_16x16x32_bf16(Ahi[kb], bl, acc[ct], 0, 0, 0);
            acc[ct] = __builtin_amdgcn_mfma_f32_16x16x32_bf16(Ahi[kb], bh, acc[ct], 0, 0, 0);
        }
    }

    // Epilogue: store h1 (bf16) + fused per-head alpha reductions (fp32).
#pragma unroll
    for (int q = 0; q < 4; ++q) {
        int n = rowbase + g * 4 + q;
        bool valid = (n < N);
        float p0s = 0.f, p1s = 0.f, p0d = 0.f, p1d = 0.f;
#pragma unroll
        for (int ct = 0; ct < 8; ++ct) {
            float h = acc[ct][q];
            if (valid) h1b[(long)n * HC1 + ct * 16 + li] = f2bf_rne(h);
            if (ct < 4) { p0s = fmaf(h, asr[ct], p0s); p0d = fmaf(h, adr[ct], p0d); }
            else        { p1s = fmaf(h, asr[ct], p1s); p1d = fmaf(h, adr[ct], p1d); }
        }
#pragma unroll
        for (int off = 8; off >= 1; off >>= 1) {
            p0s += __shfl_xor(p0s, off, 16);
            p1s += __shfl_xor(p1s, off, 16);
            p0d += __shfl_xor(p0d, off, 16);
            p1d += __shfl_xor(p1d, off, 16);
        }
        if (valid && li == 0) {
            as1[n * 2 + 0] = p0s; as1[n * 2 + 1] = p1s;
            ad1[n * 2 + 0] = p0d; ad1[n * 2 + 1] = p1d;
        }
    }
}

// ---------------------------------------------------------------------------
// Layer 1 scores: 16 lanes per node. Self-loop handled analytically.
// ---------------------------------------------------------------------------
__global__ __launch_bounds__(256)
void scores1(const int* __restrict__ eoffs, const int* __restrict__ csr,
             const float* __restrict__ as_arr, const float* __restrict__ ad_arr,
             float2* __restrict__ pe, float2* __restrict__ rden,
             float2* __restrict__ pself, int N) {
    int n = (blockIdx.x * blockDim.x + threadIdx.x) >> 4;
    int l = threadIdx.x & 15;
    if (n >= N) return;
    int s0 = eoffs[n], s1 = eoffs[n + 1];
    float2 aself = *reinterpret_cast<const float2*>(&as_arr[2 * n]);
    float ad0 = ad_arr[2 * n], ad1v = ad_arr[2 * n + 1];
    float vs0 = aself.x + ad0;  vs0 = (vs0 >= 0.f) ? vs0 : NEG_SLOPE * vs0;
    float vs1 = aself.y + ad1v; vs1 = (vs1 >= 0.f) ? vs1 : NEG_SLOPE * vs1;

    float m0 = vs0, m1 = vs1;
    for (int i = s0 + l; i < s1; i += 16) {
        int s = csr[i];
        float2 a = *reinterpret_cast<const float2*>(&as_arr[2 * s]);
        float v0 = a.x + ad0; v0 = (v0 >= 0.f) ? v0 : NEG_SLOPE * v0;
        float v1 = a.y + ad1v; v1 = (v1 >= 0.f) ? v1 : NEG_SLOPE * v1;
        m0 = fmaxf(m0, v0); m1 = fmaxf(m1, v1);
    }
#pragma unroll
    for (int off = 8; off >= 1; off >>= 1) {
        m0 = fmaxf(m0, __shfl_xor(m0, off, 16));
        m1 = fmaxf(m1, __shfl_xor(m1, off, 16));
    }
    float d0 = 0.f, d1 = 0.f;
    for (int i = s0 + l; i < s1; i += 16) {
        int s = csr[i];
        float2 a = *reinterpret_cast<const float2*>(&as_arr[2 * s]);
        float v0 = a.x + ad0; v0 = (v0 >= 0.f) ? v0 : NEG_SLOPE * v0;
        float v1 = a.y + ad1v; v1 = (v1 >= 0.f) ? v1 : NEG_SLOPE * v1;
        float p0 = __expf(v0 - m0), p1 = __expf(v1 - m1);
        d0 += p0; d1 += p1;
        pe[i] = make_float2(p0, p1);
    }
#pragma unroll
    for (int off = 8; off >= 1; off >>= 1) {
        d0 += __shfl_xor(d0, off, 16);
        d1 += __shfl_xor(d1, off, 16);
    }
    float ps0 = __expf(vs0 - m0), ps1 = __expf(vs1 - m1);
    d0 += ps0; d1 += ps1;
    if (l == 0) {
        rden[n] = make_float2(1.f / (d0 + 1e-16f), 1.f / (d1 + 1e-16f));
        pself[n] = make_float2(ps0, ps1);
    }
}

// ---------------------------------------------------------------------------
// Layer 1 gather: SpMM over bf16 h1 rows; acc seeded with p_self * h1[n].
// ---------------------------------------------------------------------------
__global__ __launch_bounds__(256)
void gather1(const int* __restrict__ eoffs, const int* __restrict__ csr,
             const float2* __restrict__ pe, const float2* __restrict__ rden,
             const float2* __restrict__ pself,
             const unsigned short* __restrict__ h1b, const float* __restrict__ b1,
             float* __restrict__ h2, int N) {
    int g = threadIdx.x >> 5;        // 0..7 node-group in block
    int l = threadIdx.x & 31;        // lane in group: cols 4l..4l+3
    int n = blockIdx.x * 8 + g;
    if (n >= N) return;
    int head = l >> 4;
    int s0 = eoffs[n], s1 = eoffs[n + 1];

    float2 ps2 = pself[n];
    float psf = head ? ps2.y : ps2.x;
    uint2 us = *reinterpret_cast<const uint2*>(&h1b[((long)n << 7) + 4 * l]);
    float4 acc;
    acc.x = bflo(us.x) * psf; acc.y = bfhi(us.x) * psf;
    acc.z = bflo(us.y) * psf; acc.w = bfhi(us.y) * psf;

    int i = s0;
    for (; i + 4 <= s1; i += 4) {
        int sa = csr[i], sb = csr[i + 1], sc = csr[i + 2], sd = csr[i + 3];
        float2 pa = pe[i], pb = pe[i + 1], pc = pe[i + 2], pd = pe[i + 3];
        uint2 ua = *reinterpret_cast<const uint2*>(&h1b[((long)sa << 7) + 4 * l]);
        uint2 ub = *reinterpret_cast<const uint2*>(&h1b[((long)sb << 7) + 4 * l]);
        uint2 uc = *reinterpret_cast<const uint2*>(&h1b[((long)sc << 7) + 4 * l]);
        uint2 ud = *reinterpret_cast<const uint2*>(&h1b[((long)sd << 7) + 4 * l]);
        float wa = head ? pa.y : pa.x;
        float wb = head ? pb.y : pb.x;
        float wc = head ? pc.y : pc.x;
        float wd = head ? pd.y : pd.x;
        acc.x = fmaf(bflo(ua.x), wa, acc.x); acc.y = fmaf(bfhi(ua.x), wa, acc.y);
        acc.z = fmaf(bflo(ua.y), wa, acc.z); acc.w = fmaf(bfhi(ua.y), wa, acc.w);
        acc.x = fmaf(bflo(ub.x), wb, acc.x); acc.y = fmaf(bfhi(ub.x), wb, acc.y);
        acc.z = fmaf(bflo(ub.y), wb, acc.z); acc.w = fmaf(bfhi(ub.y), wb, acc.w);
        acc.x = fmaf(bflo(uc.x), wc, acc.x); acc.y = fmaf(bfhi(uc.x), wc, acc.y);
        acc.z = fmaf(bflo(uc.y), wc, acc.z); acc.w = fmaf(bfhi(uc.y), wc, acc.w);
        acc.x = fmaf(bflo(ud.x), wd, acc.x); acc.y = fmaf(bfhi(ud.x), wd, acc.y);
        acc.z = fmaf(bflo(ud.y), wd, acc.z); acc.w = fmaf(bfhi(ud.y), wd, acc.w);
    }
    for (; i < s1; ++i) {
        int s = csr[i];
        float2 p2 = pe[i];
        float w = head ? p2.y : p2.x;
        uint2 u = *reinterpret_cast<const uint2*>(&h1b[((long)s << 7) + 4 * l]);
        acc.x = fmaf(bflo(u.x), w, acc.x); acc.y = fmaf(bfhi(u.x), w, acc.y);
        acc.z = fmaf(bflo(u.y), w, acc.z); acc.w = fmaf(bfhi(u.y), w, acc.w);
    }
    float2 rd = rden[n];
    float r = head ? rd.y : rd.x;
    int col = 4 * l;
    float4 bb = *reinterpret_cast<const float4*>(&b1[col]);
    float4 o;
    o.x = acc.x * r + bb.x; o.y = acc.y * r + bb.y;
    o.z = acc.z * r + bb.z; o.w = acc.w * r + bb.w;
    o.x = (o.x > 0.f) ? o.x : expm1f(o.x);
    o.y = (o.y > 0.f) ? o.y : expm1f(o.y);
    o.z = (o.z > 0.f) ? o.z : expm1f(o.z);
    o.w = (o.w > 0.f) ? o.w : expm1f(o.w);
    *reinterpret_cast<float4*>(&h2[((long)n << 7) + col]) = o;
}

// ---------------------------------------------------------------------------
// Layer 2 GEMM
// ---------------------------------------------------------------------------
__global__ __launch_bounds__(256)
void gemm2_alpha(const float* __restrict__ h2, const float* __restrict__ W2,
                 const float* __restrict__ a_src, const float* __restrict__ a_dst,
                 float* __restrict__ z, float* __restrict__ as2, float* __restrict__ ad2,
                 int N) {
    __shared__ float hs[16][FIN + 4];
    __shared__ float ws[FIN * NCLS];
    int tid = threadIdx.x;
    int n0 = blockIdx.x * 16;
    for (int i = tid; i < FIN * NCLS; i += 256) ws[i] = W2[i];
    for (int i = tid; i < 16 * FIN; i += 256) {
        int r = i >> 7, c = i & 127;
        int n = n0 + r;
        hs[r][c] = (n < N) ? h2[(long)n * FIN + c] : 0.f;
    }
    __syncthreads();

    int r = tid >> 4, c = tid & 15;
    int n = n0 + r;
    float acc = 0.f;
#pragma unroll 4
    for (int k = 0; k < FIN; ++k)
        acc = fmaf(hs[r][k], ws[k * NCLS + c], acc);

    float sa = acc * a_src[c];
    float da = acc * a_dst[c];
    for (int off = 8; off >= 1; off >>= 1) {
        sa += __shfl_xor(sa, off, 16);
        da += __shfl_xor(da, off, 16);
    }
    if (n < N) {
        z[n * NCLS + c] = acc;
        if (c == 0) { as2[n] = sa; ad2[n] = da; }
    }
}

// ---------------------------------------------------------------------------
// Layer 2 scores (H=1): 16 lanes per node, analytic self-loop.
// ---------------------------------------------------------------------------
__global__ __launch_bounds__(256)
void scores2(const int* __restrict__ eoffs, const int* __restrict__ csr,
             const float* __restrict__ as2, const float* __restrict__ ad2,
             float* __restrict__ pe2, float* __restrict__ rden2,
             float* __restrict__ pself2, int N) {
    int n = (blockIdx.x * blockDim.x + threadIdx.x) >> 4;
    int l = threadIdx.x & 15;
    if (n >= N) return;
    int s0 = eoffs[n], s1 = eoffs[n + 1];
    float adn = ad2[n];
    float vs = as2[n] + adn; vs = (vs >= 0.f) ? vs : NEG_SLOPE * vs;

    float m = vs;
    for (int i = s0 + l; i < s1; i += 16) {
        float v = as2[csr[i]] + adn;
        v = (v >= 0.f) ? v : NEG_SLOPE * v;
        m = fmaxf(m, v);
    }
#pragma unroll
    for (int off = 8; off >= 1; off >>= 1) m = fmaxf(m, __shfl_xor(m, off, 16));
    float d = 0.f;
    for (int i = s0 + l; i < s1; i += 16) {
        float v = as2[csr[i]] + adn;
        v = (v >= 0.f) ? v : NEG_SLOPE * v;
        float p = __expf(v - m);
        d += p;
        pe2[i] = p;
    }
#pragma unroll
    for (int off = 8; off >= 1; off >>= 1) d += __shfl_xor(d, off, 16);
    float ps = __expf(vs - m);
    d += ps;
    if (l == 0) {
        rden2[n] = 1.f / (d + 1e-16f);
        pself2[n] = ps;
    }
}

// ---------------------------------------------------------------------------
// Layer 2 gather + bias + log_softmax. 16 lanes per node (lane = class).
// ---------------------------------------------------------------------------
__global__ __launch_bounds__(256)
void gather2(const int* __restrict__ eoffs, const int* __restrict__ csr,
             const float* __restrict__ pe2, const float* __restrict__ rden2,
             const float* __restrict__ pself2,
             const float* __restrict__ z, const float* __restrict__ b2,
             float* __restrict__ out, int N) {
    int g = threadIdx.x >> 4;
    int l = threadIdx.x & 15;
    int n = blockIdx.x * 16 + g;
    if (n >= N) return;
    int s0 = eoffs[n], s1 = eoffs[n + 1];

    float acc = pself2[n] * z[(long)n * NCLS + l];
    int i = s0;
    for (; i + 4 <= s1; i += 4) {
        int sa = csr[i], sb = csr[i + 1], sc = csr[i + 2], sd = csr[i + 3];
        float pa = pe2[i], pb = pe2[i + 1], pc = pe2[i + 2], pd = pe2[i + 3];
        float za = z[sa * NCLS + l];
        float zb = z[sb * NCLS + l];
        float zc = z[sc * NCLS + l];
        float zd = z[sd * NCLS + l];
        acc = fmaf(za, pa, acc);
        acc = fmaf(zb, pb, acc);
        acc = fmaf(zc, pc, acc);
        acc = fmaf(zd, pd, acc);
    }
    for (; i < s1; ++i) acc = fmaf(z[csr[i] * NCLS + l], pe2[i], acc);

    float o = acc * rden2[n] + b2[l];

    float mx = o;
#pragma unroll
    for (int off = 8; off >= 1; off >>= 1) mx = fmaxf(mx, __shfl_xor(mx, off, 16));
    float ex = __expf(o - mx);
    float sum = ex;
#pragma unroll
    for (int off = 8; off >= 1; off >>= 1) sum += __shfl_xor(sum, off, 16);
    out[(long)n * NCLS + l] = o - mx - __logf(sum);
}

// ---------------------------------------------------------------------------
extern "C" void kernel_launch(void* const* d_in, const int* in_sizes, int n_in,
                              void* d_out, int out_size, void* d_ws, size_t ws_size,
                              hipStream_t stream) {
    const float* x        = (const float*)d_in[0];
    const int*   ei       = (const int*)  d_in[1];
    // d_in[2] = edge_attr (unused by reference)
    const float* W1       = (const float*)d_in[3];
    const float* att_src1 = (const float*)d_in[4];
    const float* att_dst1 = (const float*)d_in[5];
    const float* b1       = (const float*)d_in[6];
    const float* W2       = (const float*)d_in[7];
    const float* att_src2 = (const float*)d_in[8];
    const float* att_dst2 = (const float*)d_in[9];
    const float* b2       = (const float*)d_in[10];
    float* out = (float*)d_out;

    const int N = in_sizes[0] / FIN;        // 50000
    const int E = in_sizes[1] / 2;          // 800000
    const int NB = (N + 255) >> 8;          // 196 buckets
    const int EB = (E + EPB - 1) / EPB;     // 196 edge blocks

    // Workspace layout (bytes), with aliasing for layer-2 temporaries
    char* ws = (char*)d_ws;
    size_t off = 0;
    auto alloc = [&](size_t bytes) { char* p = ws + off; off += (bytes + 255) & ~(size_t)255; return p; };
    int*    blockhist     = (int*)  alloc((size_t)EB * NB * 4);
    int*    bucket_base   = (int*)  alloc((size_t)(NB + 1) * 4);
    int2*   tmp           = (int2*) alloc((size_t)E * 8);
    int*    csr           = (int*)  alloc((size_t)E * 4);
    int*    eoffs         = (int*)  alloc((size_t)(N + 1) * 4);
    unsigned short* h1b   = (unsigned short*)alloc((size_t)N * HC1 * 2);  // bf16
    float*  h2            = (float*) alloc((size_t)N * HC1 * 4);
    float*  z             = (float*) alloc((size_t)N * NCLS * 4);
    float2* pe            = (float2*)alloc((size_t)E * 8);     // layer2: pe2 aliases
    float2* rden          = (float2*)alloc((size_t)N * 8);     // layer2: rden2 aliases
    float2* pself         = (float2*)alloc((size_t)N * 8);     // layer2: pself2 aliases
    float*  as1           = (float*) alloc((size_t)N * 2 * 4); // layer2: as2 aliases
    float*  ad1           = (float*) alloc((size_t)N * 2 * 4); // layer2: ad2 aliases
    (void)ws_size;

    float* pe2    = (float*)pe;
    float* rden2  = (float*)rden;
    float* pself2 = (float*)pself;
    float* as2    = as1;
    float* ad2    = ad1;

    bcnt_kernel<<<EB, 256, 0, stream>>>(ei, blockhist, E, NB);
    bscan_kernel<<<1, 256, 0, stream>>>(blockhist, bucket_base, EB, NB);
    binA_kernel<<<EB, 256, 0, stream>>>(ei, blockhist, tmp, E, NB);
    binB_kernel<<<NB, 256, 0, stream>>>(tmp, bucket_base, csr, eoffs, E, N);

    gemm1_mfma<<<(N + 63) / 64, 256, 0, stream>>>(
        x, W1, att_src1, att_dst1, h1b, as1, ad1, N);
    scores1<<<(N + 15) / 16, 256, 0, stream>>>(eoffs, csr, as1, ad1, pe, rden, pself, N);
    gather1<<<(N + 7) / 8, 256, 0, stream>>>(eoffs, csr, pe, rden, pself, h1b, b1, h2, N);

    gemm2_alpha<<<(N + 15) / 16, 256, 0, stream>>>(
        h2, W2, att_src2, att_dst2, z, as2, ad2, N);
    scores2<<<(N + 15) / 16, 256, 0, stream>>>(eoffs, csr, as2, ad2, pe2, rden2, pself2, N);
    gather2<<<(N + 15) / 16, 256, 0, stream>>>(eoffs, csr, pe2, rden2, pself2, z, b2, out, N);
}

// Round 10
// 148.621 us; speedup vs baseline: 1.4183x; 1.4183x over previous
//
#include <hip/hip_runtime.h>
#include <math.h>

// Problem constants (match reference)
#define FIN   128
#define HC1   128   // H*C for layer 1
#define NCLS  16
#define NEG_SLOPE 0.2f

typedef __attribute__((ext_vector_type(8))) short bf16x8;
typedef __attribute__((ext_vector_type(4))) float f32x4;

__device__ __forceinline__ unsigned short f2bf_rne(float f) {
    unsigned int u = __float_as_uint(f);
    unsigned int r = u + 0x7FFFu + ((u >> 16) & 1u);
    return (unsigned short)(r >> 16);
}
__device__ __forceinline__ float bf2f(unsigned short h) {
    return __uint_as_float(((unsigned int)h) << 16);
}
__device__ __forceinline__ float bflo(unsigned int u) { return __uint_as_float(u << 16); }
__device__ __forceinline__ float bfhi(unsigned int u) { return __uint_as_float(u & 0xFFFF0000u); }

// ---------------------------------------------------------------------------
// CSR build via two-level bucket sort (bucket = dst>>8).
// Memset-free + global-atomic-free. blockhist is a 2D [EB][NB] matrix;
// colscan (parallel per column) + bscan2 (bucket scan) replace R9's serial
// rewrite. binA does ONE pass using precomputed per-(block,bucket) bases.
// Self-loops are NOT in the CSR; scores/gather handle them analytically.
// ---------------------------------------------------------------------------
#define EPB 4096   // edges per block in bcnt/binA  (EB = ceil(E/EPB) must be <=256)

__global__ __launch_bounds__(256)
void bcnt_kernel(const int* __restrict__ ei, int* __restrict__ blockhist,
                 int E, int NB) {
    __shared__ int h[256];
    int tid = threadIdx.x;
    h[tid] = 0;
    __syncthreads();
    int base = blockIdx.x * EPB;
#pragma unroll
    for (int j = 0; j < EPB / 256; ++j) {
        int e = base + j * 256 + tid;
        if (e < E) atomicAdd(&h[ei[E + e] >> 8], 1);
    }
    __syncthreads();
    if (tid < NB) blockhist[blockIdx.x * NB + tid] = h[tid];
}

// NB blocks; block t scans its COLUMN of blockhist (one element/thread).
__global__ __launch_bounds__(256)
void colscan_kernel(int* __restrict__ blockhist, int* __restrict__ colsum,
                    int EB, int NB) {
    __shared__ int lds[256];
    int t = blockIdx.x;       // bucket (column)
    int b = threadIdx.x;      // edge-block (row)
    int v = (b < EB) ? blockhist[b * NB + t] : 0;
    lds[b] = v;
    __syncthreads();
    for (int off = 1; off < 256; off <<= 1) {
        int u = (b >= off) ? lds[b - off] : 0;
        __syncthreads();
        lds[b] += u;
        __syncthreads();
    }
    if (b < EB) blockhist[b * NB + t] = lds[b] - v;   // excl offset within bucket
    if (b == 255) colsum[t] = lds[255];
}

// 1 block: exclusive scan of colsum -> bucket_base[0..NB].
__global__ __launch_bounds__(256)
void bscan2_kernel(const int* __restrict__ colsum, int* __restrict__ bucket_base,
                   int NB) {
    __shared__ int lds[256];
    int t = threadIdx.x;
    int v = (t < NB) ? colsum[t] : 0;
    lds[t] = v;
    __syncthreads();
    for (int off = 1; off < 256; off <<= 1) {
        int u = (t >= off) ? lds[t - off] : 0;
        __syncthreads();
        lds[t] += u;
        __syncthreads();
    }
    if (t < NB) bucket_base[t] = lds[t] - v;
    if (t == 255) bucket_base[NB] = lds[255];   // == E
}

__global__ __launch_bounds__(256)
void binA_kernel(const int* __restrict__ ei, const int* __restrict__ blockhist,
                 const int* __restrict__ bucket_base,
                 int2* __restrict__ tmp, int E, int NB) {
    __shared__ int h[256];    // local cursors
    __shared__ int bb[256];   // this block's global base per bucket
    int tid = threadIdx.x;
    h[tid] = 0;
    if (tid < NB) bb[tid] = blockhist[blockIdx.x * NB + tid] + bucket_base[tid];
    __syncthreads();
    int base = blockIdx.x * EPB;
#pragma unroll
    for (int j = 0; j < EPB / 256; ++j) {
        int e = base + j * 256 + tid;
        if (e < E) {
            int s = ei[e], d = ei[E + e];
            int b = d >> 8;
            int r = atomicAdd(&h[b], 1);
            tmp[bb[b] + r] = make_int2(s, d);
        }
    }
}

// One block per bucket: sorts its bucket by node, writes csr densely and
// emits eoffs (global CSR offsets) directly.
__global__ __launch_bounds__(256)
void binB_kernel(const int2* __restrict__ tmp, const int* __restrict__ bucket_base,
                 int* __restrict__ csr, int* __restrict__ eoffs, int E, int N) {
    __shared__ int cnt[256];
    __shared__ int lds[256];
    __shared__ int cur[256];
    int b = blockIdx.x, t = threadIdx.x;
    int lo = bucket_base[b], hi = bucket_base[b + 1];
    cnt[t] = 0;
    __syncthreads();
    for (int i = lo + t; i < hi; i += 256)
        atomicAdd(&cnt[tmp[i].y & 255], 1);
    __syncthreads();
    int v = cnt[t];
    lds[t] = v;
    __syncthreads();
    for (int off = 1; off < 256; off <<= 1) {
        int u = (t >= off) ? lds[t - off] : 0;
        __syncthreads();
        lds[t] += u;
        __syncthreads();
    }
    int excl = lds[t] - v;
    int node = b * 256 + t;
    if (node < N) eoffs[node] = lo + excl;
    if (b == 0 && t == 0) eoffs[N] = E;
    cur[t] = lo + excl;
    __syncthreads();
    for (int i = lo + t; i < hi; i += 256) {
        int2 e = tmp[i];
        int p = atomicAdd(&cur[e.y & 255], 1);
        csr[p] = e.x;
    }
}

// ---------------------------------------------------------------------------
// Layer 1 GEMM via split-bf16 MFMA: h1 = x @ W1, ~fp32 accuracy.
// h1 stored bf16; alpha scalars from full fp32 accumulator.
// ---------------------------------------------------------------------------
__global__ __launch_bounds__(256)
void gemm1_mfma(const float* __restrict__ x, const float* __restrict__ W,
                const float* __restrict__ a_src, const float* __restrict__ a_dst,
                unsigned short* __restrict__ h1b, float* __restrict__ as1,
                float* __restrict__ ad1, int N) {
    __shared__ unsigned short whi[FIN * HC1];   // 32 KB, fragment-ordered
    __shared__ unsigned short wlo[FIN * HC1];   // 32 KB
    int tid = threadIdx.x;

#pragma unroll
    for (int i = 0; i < 64; ++i) {
        int idx = tid + i * 256;            // 0..16383, coalesced
        int k = idx >> 7, c = idx & 127;
        float v = W[idx];
        unsigned short hb = f2bf_rne(v);
        unsigned short lb = f2bf_rne(v - bf2f(hb));
        int kb = k >> 5, kk = k & 31;
        int g = kk >> 3, j = kk & 7;
        int ct = c >> 4, li = c & 15;
        int off = ((kb * 8 + ct) * 64 + g * 16 + li) * 8 + j;
        whi[off] = hb;
        wlo[off] = lb;
    }

    int wid = tid >> 6, lane = tid & 63;
    int li = lane & 15, g = lane >> 4;
    int rowbase = blockIdx.x * 64 + wid * 16;

    int arow = rowbase + li;
    if (arow >= N) arow = N - 1;            // clamp; invalid rows never stored
    const float* xp = x + (long)arow * FIN + g * 8;
    bf16x8 Ahi[4], Alo[4];
#pragma unroll
    for (int kb = 0; kb < 4; ++kb) {
        float4 v0 = *reinterpret_cast<const float4*>(xp + kb * 32);
        float4 v1 = *reinterpret_cast<const float4*>(xp + kb * 32 + 4);
        float vs0 = v0.x, vs1 = v0.y, vs2 = v0.z, vs3 = v0.w;
        float vs4 = v1.x, vs5 = v1.y, vs6 = v1.z, vs7 = v1.w;
        bf16x8 h8, l8;
        unsigned short hb;
        hb = f2bf_rne(vs0); h8[0] = (short)hb; l8[0] = (short)f2bf_rne(vs0 - bf2f(hb));
        hb = f2bf_rne(vs1); h8[1] = (short)hb; l8[1] = (short)f2bf_rne(vs1 - bf2f(hb));
        hb = f2bf_rne(vs2); h8[2] = (short)hb; l8[2] = (short)f2bf_rne(vs2 - bf2f(hb));
        hb = f2bf_rne(vs3); h8[3] = (short)hb; l8[3] = (short)f2bf_rne(vs3 - bf2f(hb));
        hb = f2bf_rne(vs4); h8[4] = (short)hb; l8[4] = (short)f2bf_rne(vs4 - bf2f(hb));
        hb = f2bf_rne(vs5); h8[5] = (short)hb; l8[5] = (short)f2bf_rne(vs5 - bf2f(hb));
        hb = f2bf_rne(vs6); h8[6] = (short)hb; l8[6] = (short)f2bf_rne(vs6 - bf2f(hb));
        hb = f2bf_rne(vs7); h8[7] = (short)hb; l8[7] = (short)f2bf_rne(vs7 - bf2f(hb));
        Ahi[kb] = h8; Alo[kb] = l8;
    }

    float asr[8], adr[8];
#pragma unroll
    for (int ct = 0; ct < 8; ++ct) {
        asr[ct] = a_src[ct * 16 + li];
        adr[ct] = a_dst[ct * 16 + li];
    }

    __syncthreads();

    f32x4 acc[8];
#pragma unroll
    for (int ct = 0; ct < 8; ++ct) acc[ct] = (f32x4){0.f, 0.f, 0.f, 0.f};

#pragma unroll
    for (int kb = 0; kb < 4; ++kb) {
#pragma unroll
        for (int ct = 0; ct < 8; ++ct) {
            bf16x8 bh = *reinterpret_cast<const bf16x8*>(&whi[((kb * 8 + ct) * 64 + lane) * 8]);
            bf16x8 bl = *reinterpret_cast<const bf16x8*>(&wlo[((kb * 8 + ct) * 64 + lane) * 8]);
            acc[ct] = __builtin_amdgcn_mfma_f32_16x16x32_bf16(Alo[kb], bh, acc[ct], 0, 0, 0);
            acc[ct] = __builtin_amdgcn_mfma_f32_16x16x32_bf16(Ahi[kb], bl, acc[ct], 0, 0, 0);
            acc[ct] = __builtin_amdgcn_mfma_f32_16x16x32_bf16(Ahi[kb], bh, acc[ct], 0, 0, 0);
        }
    }

    // Epilogue: store h1 (bf16) + fused per-head alpha reductions (fp32).
#pragma unroll
    for (int q = 0; q < 4; ++q) {
        int n = rowbase + g * 4 + q;
        bool valid = (n < N);
        float p0s = 0.f, p1s = 0.f, p0d = 0.f, p1d = 0.f;
#pragma unroll
        for (int ct = 0; ct < 8; ++ct) {
            float h = acc[ct][q];
            if (valid) h1b[(long)n * HC1 + ct * 16 + li] = f2bf_rne(h);
            if (ct < 4) { p0s = fmaf(h, asr[ct], p0s); p0d = fmaf(h, adr[ct], p0d); }
            else        { p1s = fmaf(h, asr[ct], p1s); p1d = fmaf(h, adr[ct], p1d); }
        }
#pragma unroll
        for (int off = 8; off >= 1; off >>= 1) {
            p0s += __shfl_xor(p0s, off, 16);
            p1s += __shfl_xor(p1s, off, 16);
            p0d += __shfl_xor(p0d, off, 16);
            p1d += __shfl_xor(p1d, off, 16);
        }
        if (valid && li == 0) {
            as1[n * 2 + 0] = p0s; as1[n * 2 + 1] = p1s;
            ad1[n * 2 + 0] = p0d; ad1[n * 2 + 1] = p1d;
        }
    }
}

// ---------------------------------------------------------------------------
// Layer 1 scores: 16 lanes per node. Self-loop handled analytically.
// ---------------------------------------------------------------------------
__global__ __launch_bounds__(256)
void scores1(const int* __restrict__ eoffs, const int* __restrict__ csr,
             const float* __restrict__ as_arr, const float* __restrict__ ad_arr,
             float2* __restrict__ pe, float2* __restrict__ rden,
             float2* __restrict__ pself, int N) {
    int n = (blockIdx.x * blockDim.x + threadIdx.x) >> 4;
    int l = threadIdx.x & 15;
    if (n >= N) return;
    int s0 = eoffs[n], s1 = eoffs[n + 1];
    float2 aself = *reinterpret_cast<const float2*>(&as_arr[2 * n]);
    float ad0 = ad_arr[2 * n], ad1v = ad_arr[2 * n + 1];
    float vs0 = aself.x + ad0;  vs0 = (vs0 >= 0.f) ? vs0 : NEG_SLOPE * vs0;
    float vs1 = aself.y + ad1v; vs1 = (vs1 >= 0.f) ? vs1 : NEG_SLOPE * vs1;

    float m0 = vs0, m1 = vs1;
    for (int i = s0 + l; i < s1; i += 16) {
        int s = csr[i];
        float2 a = *reinterpret_cast<const float2*>(&as_arr[2 * s]);
        float v0 = a.x + ad0; v0 = (v0 >= 0.f) ? v0 : NEG_SLOPE * v0;
        float v1 = a.y + ad1v; v1 = (v1 >= 0.f) ? v1 : NEG_SLOPE * v1;
        m0 = fmaxf(m0, v0); m1 = fmaxf(m1, v1);
    }
#pragma unroll
    for (int off = 8; off >= 1; off >>= 1) {
        m0 = fmaxf(m0, __shfl_xor(m0, off, 16));
        m1 = fmaxf(m1, __shfl_xor(m1, off, 16));
    }
    float d0 = 0.f, d1 = 0.f;
    for (int i = s0 + l; i < s1; i += 16) {
        int s = csr[i];
        float2 a = *reinterpret_cast<const float2*>(&as_arr[2 * s]);
        float v0 = a.x + ad0; v0 = (v0 >= 0.f) ? v0 : NEG_SLOPE * v0;
        float v1 = a.y + ad1v; v1 = (v1 >= 0.f) ? v1 : NEG_SLOPE * v1;
        float p0 = __expf(v0 - m0), p1 = __expf(v1 - m1);
        d0 += p0; d1 += p1;
        pe[i] = make_float2(p0, p1);
    }
#pragma unroll
    for (int off = 8; off >= 1; off >>= 1) {
        d0 += __shfl_xor(d0, off, 16);
        d1 += __shfl_xor(d1, off, 16);
    }
    float ps0 = __expf(vs0 - m0), ps1 = __expf(vs1 - m1);
    d0 += ps0; d1 += ps1;
    if (l == 0) {
        rden[n] = make_float2(1.f / (d0 + 1e-16f), 1.f / (d1 + 1e-16f));
        pself[n] = make_float2(ps0, ps1);
    }
}

// ---------------------------------------------------------------------------
// Layer 1 gather: SpMM over bf16 h1 rows; acc seeded with p_self * h1[n].
// ---------------------------------------------------------------------------
__global__ __launch_bounds__(256)
void gather1(const int* __restrict__ eoffs, const int* __restrict__ csr,
             const float2* __restrict__ pe, const float2* __restrict__ rden,
             const float2* __restrict__ pself,
             const unsigned short* __restrict__ h1b, const float* __restrict__ b1,
             float* __restrict__ h2, int N) {
    int g = threadIdx.x >> 5;        // 0..7 node-group in block
    int l = threadIdx.x & 31;        // lane in group: cols 4l..4l+3
    int n = blockIdx.x * 8 + g;
    if (n >= N) return;
    int head = l >> 4;
    int s0 = eoffs[n], s1 = eoffs[n + 1];

    float2 ps2 = pself[n];
    float psf = head ? ps2.y : ps2.x;
    uint2 us = *reinterpret_cast<const uint2*>(&h1b[((long)n << 7) + 4 * l]);
    float4 acc;
    acc.x = bflo(us.x) * psf; acc.y = bfhi(us.x) * psf;
    acc.z = bflo(us.y) * psf; acc.w = bfhi(us.y) * psf;

    int i = s0;
    for (; i + 4 <= s1; i += 4) {
        int sa = csr[i], sb = csr[i + 1], sc = csr[i + 2], sd = csr[i + 3];
        float2 pa = pe[i], pb = pe[i + 1], pc = pe[i + 2], pd = pe[i + 3];
        uint2 ua = *reinterpret_cast<const uint2*>(&h1b[((long)sa << 7) + 4 * l]);
        uint2 ub = *reinterpret_cast<const uint2*>(&h1b[((long)sb << 7) + 4 * l]);
        uint2 uc = *reinterpret_cast<const uint2*>(&h1b[((long)sc << 7) + 4 * l]);
        uint2 ud = *reinterpret_cast<const uint2*>(&h1b[((long)sd << 7) + 4 * l]);
        float wa = head ? pa.y : pa.x;
        float wb = head ? pb.y : pb.x;
        float wc = head ? pc.y : pc.x;
        float wd = head ? pd.y : pd.x;
        acc.x = fmaf(bflo(ua.x), wa, acc.x); acc.y = fmaf(bfhi(ua.x), wa, acc.y);
        acc.z = fmaf(bflo(ua.y), wa, acc.z); acc.w = fmaf(bfhi(ua.y), wa, acc.w);
        acc.x = fmaf(bflo(ub.x), wb, acc.x); acc.y = fmaf(bfhi(ub.x), wb, acc.y);
        acc.z = fmaf(bflo(ub.y), wb, acc.z); acc.w = fmaf(bfhi(ub.y), wb, acc.w);
        acc.x = fmaf(bflo(uc.x), wc, acc.x); acc.y = fmaf(bfhi(uc.x), wc, acc.y);
        acc.z = fmaf(bflo(uc.y), wc, acc.z); acc.w = fmaf(bfhi(uc.y), wc, acc.w);
        acc.x = fmaf(bflo(ud.x), wd, acc.x); acc.y = fmaf(bfhi(ud.x), wd, acc.y);
        acc.z = fmaf(bflo(ud.y), wd, acc.z); acc.w = fmaf(bfhi(ud.y), wd, acc.w);
    }
    for (; i < s1; ++i) {
        int s = csr[i];
        float2 p2 = pe[i];
        float w = head ? p2.y : p2.x;
        uint2 u = *reinterpret_cast<const uint2*>(&h1b[((long)s << 7) + 4 * l]);
        acc.x = fmaf(bflo(u.x), w, acc.x); acc.y = fmaf(bfhi(u.x), w, acc.y);
        acc.z = fmaf(bflo(u.y), w, acc.z); acc.w = fmaf(bfhi(u.y), w, acc.w);
    }
    float2 rd = rden[n];
    float r = head ? rd.y : rd.x;
    int col = 4 * l;
    float4 bb = *reinterpret_cast<const float4*>(&b1[col]);
    float4 o;
    o.x = acc.x * r + bb.x; o.y = acc.y * r + bb.y;
    o.z = acc.z * r + bb.z; o.w = acc.w * r + bb.w;
    o.x = (o.x > 0.f) ? o.x : expm1f(o.x);
    o.y = (o.y > 0.f) ? o.y : expm1f(o.y);
    o.z = (o.z > 0.f) ? o.z : expm1f(o.z);
    o.w = (o.w > 0.f) ? o.w : expm1f(o.w);
    *reinterpret_cast<float4*>(&h2[((long)n << 7) + col]) = o;
}

// ---------------------------------------------------------------------------
// Layer 2 GEMM
// ---------------------------------------------------------------------------
__global__ __launch_bounds__(256)
void gemm2_alpha(const float* __restrict__ h2, const float* __restrict__ W2,
                 const float* __restrict__ a_src, const float* __restrict__ a_dst,
                 float* __restrict__ z, float* __restrict__ as2, float* __restrict__ ad2,
                 int N) {
    __shared__ float hs[16][FIN + 4];
    __shared__ float ws[FIN * NCLS];
    int tid = threadIdx.x;
    int n0 = blockIdx.x * 16;
    for (int i = tid; i < FIN * NCLS; i += 256) ws[i] = W2[i];
    for (int i = tid; i < 16 * FIN; i += 256) {
        int r = i >> 7, c = i & 127;
        int n = n0 + r;
        hs[r][c] = (n < N) ? h2[(long)n * FIN + c] : 0.f;
    }
    __syncthreads();

    int r = tid >> 4, c = tid & 15;
    int n = n0 + r;
    float acc = 0.f;
#pragma unroll 4
    for (int k = 0; k < FIN; ++k)
        acc = fmaf(hs[r][k], ws[k * NCLS + c], acc);

    float sa = acc * a_src[c];
    float da = acc * a_dst[c];
    for (int off = 8; off >= 1; off >>= 1) {
        sa += __shfl_xor(sa, off, 16);
        da += __shfl_xor(da, off, 16);
    }
    if (n < N) {
        z[n * NCLS + c] = acc;
        if (c == 0) { as2[n] = sa; ad2[n] = da; }
    }
}

// ---------------------------------------------------------------------------
// Layer 2 scores (H=1): 16 lanes per node, analytic self-loop.
// ---------------------------------------------------------------------------
__global__ __launch_bounds__(256)
void scores2(const int* __restrict__ eoffs, const int* __restrict__ csr,
             const float* __restrict__ as2, const float* __restrict__ ad2,
             float* __restrict__ pe2, float* __restrict__ rden2,
             float* __restrict__ pself2, int N) {
    int n = (blockIdx.x * blockDim.x + threadIdx.x) >> 4;
    int l = threadIdx.x & 15;
    if (n >= N) return;
    int s0 = eoffs[n], s1 = eoffs[n + 1];
    float adn = ad2[n];
    float vs = as2[n] + adn; vs = (vs >= 0.f) ? vs : NEG_SLOPE * vs;

    float m = vs;
    for (int i = s0 + l; i < s1; i += 16) {
        float v = as2[csr[i]] + adn;
        v = (v >= 0.f) ? v : NEG_SLOPE * v;
        m = fmaxf(m, v);
    }
#pragma unroll
    for (int off = 8; off >= 1; off >>= 1) m = fmaxf(m, __shfl_xor(m, off, 16));
    float d = 0.f;
    for (int i = s0 + l; i < s1; i += 16) {
        float v = as2[csr[i]] + adn;
        v = (v >= 0.f) ? v : NEG_SLOPE * v;
        float p = __expf(v - m);
        d += p;
        pe2[i] = p;
    }
#pragma unroll
    for (int off = 8; off >= 1; off >>= 1) d += __shfl_xor(d, off, 16);
    float ps = __expf(vs - m);
    d += ps;
    if (l == 0) {
        rden2[n] = 1.f / (d + 1e-16f);
        pself2[n] = ps;
    }
}

// ---------------------------------------------------------------------------
// Layer 2 gather + bias + log_softmax. 16 lanes per node (lane = class).
// ---------------------------------------------------------------------------
__global__ __launch_bounds__(256)
void gather2(const int* __restrict__ eoffs, const int* __restrict__ csr,
             const float* __restrict__ pe2, const float* __restrict__ rden2,
             const float* __restrict__ pself2,
             const float* __restrict__ z, const float* __restrict__ b2,
             float* __restrict__ out, int N) {
    int g = threadIdx.x >> 4;
    int l = threadIdx.x & 15;
    int n = blockIdx.x * 16 + g;
    if (n >= N) return;
    int s0 = eoffs[n], s1 = eoffs[n + 1];

    float acc = pself2[n] * z[(long)n * NCLS + l];
    int i = s0;
    for (; i + 4 <= s1; i += 4) {
        int sa = csr[i], sb = csr[i + 1], sc = csr[i + 2], sd = csr[i + 3];
        float pa = pe2[i], pb = pe2[i + 1], pc = pe2[i + 2], pd = pe2[i + 3];
        float za = z[sa * NCLS + l];
        float zb = z[sb * NCLS + l];
        float zc = z[sc * NCLS + l];
        float zd = z[sd * NCLS + l];
        acc = fmaf(za, pa, acc);
        acc = fmaf(zb, pb, acc);
        acc = fmaf(zc, pc, acc);
        acc = fmaf(zd, pd, acc);
    }
    for (; i < s1; ++i) acc = fmaf(z[csr[i] * NCLS + l], pe2[i], acc);

    float o = acc * rden2[n] + b2[l];

    float mx = o;
#pragma unroll
    for (int off = 8; off >= 1; off >>= 1) mx = fmaxf(mx, __shfl_xor(mx, off, 16));
    float ex = __expf(o - mx);
    float sum = ex;
#pragma unroll
    for (int off = 8; off >= 1; off >>= 1) sum += __shfl_xor(sum, off, 16);
    out[(long)n * NCLS + l] = o - mx - __logf(sum);
}

// ---------------------------------------------------------------------------
extern "C" void kernel_launch(void* const* d_in, const int* in_sizes, int n_in,
                              void* d_out, int out_size, void* d_ws, size_t ws_size,
                              hipStream_t stream) {
    const float* x        = (const float*)d_in[0];
    const int*   ei       = (const int*)  d_in[1];
    // d_in[2] = edge_attr (unused by reference)
    const float* W1       = (const float*)d_in[3];
    const float* att_src1 = (const float*)d_in[4];
    const float* att_dst1 = (const float*)d_in[5];
    const float* b1       = (const float*)d_in[6];
    const float* W2       = (const float*)d_in[7];
    const float* att_src2 = (const float*)d_in[8];
    const float* att_dst2 = (const float*)d_in[9];
    const float* b2       = (const float*)d_in[10];
    float* out = (float*)d_out;

    const int N = in_sizes[0] / FIN;        // 50000
    const int E = in_sizes[1] / 2;          // 800000
    const int NB = (N + 255) >> 8;          // 196 buckets
    const int EB = (E + EPB - 1) / EPB;     // 196 edge blocks (<=256)

    // Workspace layout (bytes), with aliasing for layer-2 temporaries
    char* ws = (char*)d_ws;
    size_t off = 0;
    auto alloc = [&](size_t bytes) { char* p = ws + off; off += (bytes + 255) & ~(size_t)255; return p; };
    int*    blockhist     = (int*)  alloc((size_t)EB * NB * 4);
    int*    colsum        = (int*)  alloc((size_t)NB * 4);
    int*    bucket_base   = (int*)  alloc((size_t)(NB + 1) * 4);
    int2*   tmp           = (int2*) alloc((size_t)E * 8);
    int*    csr           = (int*)  alloc((size_t)E * 4);
    int*    eoffs         = (int*)  alloc((size_t)(N + 1) * 4);
    unsigned short* h1b   = (unsigned short*)alloc((size_t)N * HC1 * 2);  // bf16
    float*  h2            = (float*) alloc((size_t)N * HC1 * 4);
    float*  z             = (float*) alloc((size_t)N * NCLS * 4);
    float2* pe            = (float2*)alloc((size_t)E * 8);     // layer2: pe2 aliases
    float2* rden          = (float2*)alloc((size_t)N * 8);     // layer2: rden2 aliases
    float2* pself         = (float2*)alloc((size_t)N * 8);     // layer2: pself2 aliases
    float*  as1           = (float*) alloc((size_t)N * 2 * 4); // layer2: as2 aliases
    float*  ad1           = (float*) alloc((size_t)N * 2 * 4); // layer2: ad2 aliases
    (void)ws_size;

    float* pe2    = (float*)pe;
    float* rden2  = (float*)rden;
    float* pself2 = (float*)pself;
    float* as2    = as1;
    float* ad2    = ad1;

    bcnt_kernel<<<EB, 256, 0, stream>>>(ei, blockhist, E, NB);
    colscan_kernel<<<NB, 256, 0, stream>>>(blockhist, colsum, EB, NB);
    bscan2_kernel<<<1, 256, 0, stream>>>(colsum, bucket_base, NB);
    binA_kernel<<<EB, 256, 0, stream>>>(ei, blockhist, bucket_base, tmp, E, NB);
    binB_kernel<<<NB, 256, 0, stream>>>(tmp, bucket_base, csr, eoffs, E, N);

    gemm1_mfma<<<(N + 63) / 64, 256, 0, stream>>>(
        x, W1, att_src1, att_dst1, h1b, as1, ad1, N);
    scores1<<<(N + 15) / 16, 256, 0, stream>>>(eoffs, csr, as1, ad1, pe, rden, pself, N);
    gather1<<<(N + 7) / 8, 256, 0, stream>>>(eoffs, csr, pe, rden, pself, h1b, b1, h2, N);

    gemm2_alpha<<<(N + 15) / 16, 256, 0, stream>>>(
        h2, W2, att_src2, att_dst2, z, as2, ad2, N);
    scores2<<<(N + 15) / 16, 256, 0, stream>>>(eoffs, csr, as2, ad2, pe2, rden2, pself2, N);
    gather2<<<(N + 15) / 16, 256, 0, stream>>>(eoffs, csr, pe2, rden2, pself2, z, b2, out, N);
}

// Round 11
// 134.399 us; speedup vs baseline: 1.5683x; 1.1058x over previous
//
#include <hip/hip_runtime.h>
#include <math.h>

// Problem constants (match reference)
#define FIN   128
#define HC1   128   // H*C for layer 1
#define NCLS  16
#define NEG_SLOPE 0.2f

typedef __attribute__((ext_vector_type(8))) short bf16x8;
typedef __attribute__((ext_vector_type(4))) float f32x4;

__device__ __forceinline__ unsigned short f2bf_rne(float f) {
    unsigned int u = __float_as_uint(f);
    unsigned int r = u + 0x7FFFu + ((u >> 16) & 1u);
    return (unsigned short)(r >> 16);
}
__device__ __forceinline__ float bf2f(unsigned short h) {
    return __uint_as_float(((unsigned int)h) << 16);
}
__device__ __forceinline__ float bflo(unsigned int u) { return __uint_as_float(u << 16); }
__device__ __forceinline__ float bfhi(unsigned int u) { return __uint_as_float(u & 0xFFFF0000u); }

// ---------------------------------------------------------------------------
// CSR build via two-level bucket sort (bucket = dst>>8). Memset-free,
// global-atomic-free (R10 structure: bcnt -> colscan -> bscan2 -> binA -> binB).
// Self-loops are NOT in the CSR; fused gathers handle them analytically.
// ---------------------------------------------------------------------------
#define EPB 4096   // edges per block in bcnt/binA  (EB = ceil(E/EPB) must be <=256)

__global__ __launch_bounds__(256)
void bcnt_kernel(const int* __restrict__ ei, int* __restrict__ blockhist,
                 int E, int NB) {
    __shared__ int h[256];
    int tid = threadIdx.x;
    h[tid] = 0;
    __syncthreads();
    int base = blockIdx.x * EPB;
#pragma unroll
    for (int j = 0; j < EPB / 256; ++j) {
        int e = base + j * 256 + tid;
        if (e < E) atomicAdd(&h[ei[E + e] >> 8], 1);
    }
    __syncthreads();
    if (tid < NB) blockhist[blockIdx.x * NB + tid] = h[tid];
}

// NB blocks; block t scans its COLUMN of blockhist (one element/thread).
__global__ __launch_bounds__(256)
void colscan_kernel(int* __restrict__ blockhist, int* __restrict__ colsum,
                    int EB, int NB) {
    __shared__ int lds[256];
    int t = blockIdx.x;       // bucket (column)
    int b = threadIdx.x;      // edge-block (row)
    int v = (b < EB) ? blockhist[b * NB + t] : 0;
    lds[b] = v;
    __syncthreads();
    for (int off = 1; off < 256; off <<= 1) {
        int u = (b >= off) ? lds[b - off] : 0;
        __syncthreads();
        lds[b] += u;
        __syncthreads();
    }
    if (b < EB) blockhist[b * NB + t] = lds[b] - v;   // excl offset within bucket
    if (b == 255) colsum[t] = lds[255];
}

// 1 block: exclusive scan of colsum -> bucket_base[0..NB].
__global__ __launch_bounds__(256)
void bscan2_kernel(const int* __restrict__ colsum, int* __restrict__ bucket_base,
                   int NB) {
    __shared__ int lds[256];
    int t = threadIdx.x;
    int v = (t < NB) ? colsum[t] : 0;
    lds[t] = v;
    __syncthreads();
    for (int off = 1; off < 256; off <<= 1) {
        int u = (t >= off) ? lds[t - off] : 0;
        __syncthreads();
        lds[t] += u;
        __syncthreads();
    }
    if (t < NB) bucket_base[t] = lds[t] - v;
    if (t == 255) bucket_base[NB] = lds[255];   // == E
}

__global__ __launch_bounds__(256)
void binA_kernel(const int* __restrict__ ei, const int* __restrict__ blockhist,
                 const int* __restrict__ bucket_base,
                 int2* __restrict__ tmp, int E, int NB) {
    __shared__ int h[256];    // local cursors
    __shared__ int bb[256];   // this block's global base per bucket
    int tid = threadIdx.x;
    h[tid] = 0;
    if (tid < NB) bb[tid] = blockhist[blockIdx.x * NB + tid] + bucket_base[tid];
    __syncthreads();
    int base = blockIdx.x * EPB;
#pragma unroll
    for (int j = 0; j < EPB / 256; ++j) {
        int e = base + j * 256 + tid;
        if (e < E) {
            int s = ei[e], d = ei[E + e];
            int b = d >> 8;
            int r = atomicAdd(&h[b], 1);
            tmp[bb[b] + r] = make_int2(s, d);
        }
    }
}

// One block per bucket: sorts its bucket by node, writes csr densely and
// emits eoffs (global CSR offsets) directly.
__global__ __launch_bounds__(256)
void binB_kernel(const int2* __restrict__ tmp, const int* __restrict__ bucket_base,
                 int* __restrict__ csr, int* __restrict__ eoffs, int E, int N) {
    __shared__ int cnt[256];
    __shared__ int lds[256];
    __shared__ int cur[256];
    int b = blockIdx.x, t = threadIdx.x;
    int lo = bucket_base[b], hi = bucket_base[b + 1];
    cnt[t] = 0;
    __syncthreads();
    for (int i = lo + t; i < hi; i += 256)
        atomicAdd(&cnt[tmp[i].y & 255], 1);
    __syncthreads();
    int v = cnt[t];
    lds[t] = v;
    __syncthreads();
    for (int off = 1; off < 256; off <<= 1) {
        int u = (t >= off) ? lds[t - off] : 0;
        __syncthreads();
        lds[t] += u;
        __syncthreads();
    }
    int excl = lds[t] - v;
    int node = b * 256 + t;
    if (node < N) eoffs[node] = lo + excl;
    if (b == 0 && t == 0) eoffs[N] = E;
    cur[t] = lo + excl;
    __syncthreads();
    for (int i = lo + t; i < hi; i += 256) {
        int2 e = tmp[i];
        int p = atomicAdd(&cur[e.y & 255], 1);
        csr[p] = e.x;
    }
}

// ---------------------------------------------------------------------------
// Layer 1 GEMM via split-bf16 MFMA: h1 = x @ W1, ~fp32 accuracy.
// h1 stored bf16; alpha scalars from full fp32 accumulator.
// ---------------------------------------------------------------------------
__global__ __launch_bounds__(256)
void gemm1_mfma(const float* __restrict__ x, const float* __restrict__ W,
                const float* __restrict__ a_src, const float* __restrict__ a_dst,
                unsigned short* __restrict__ h1b, float* __restrict__ as1,
                float* __restrict__ ad1, int N) {
    __shared__ unsigned short whi[FIN * HC1];   // 32 KB, fragment-ordered
    __shared__ unsigned short wlo[FIN * HC1];   // 32 KB
    int tid = threadIdx.x;

#pragma unroll
    for (int i = 0; i < 64; ++i) {
        int idx = tid + i * 256;            // 0..16383, coalesced
        int k = idx >> 7, c = idx & 127;
        float v = W[idx];
        unsigned short hb = f2bf_rne(v);
        unsigned short lb = f2bf_rne(v - bf2f(hb));
        int kb = k >> 5, kk = k & 31;
        int g = kk >> 3, j = kk & 7;
        int ct = c >> 4, li = c & 15;
        int off = ((kb * 8 + ct) * 64 + g * 16 + li) * 8 + j;
        whi[off] = hb;
        wlo[off] = lb;
    }

    int wid = tid >> 6, lane = tid & 63;
    int li = lane & 15, g = lane >> 4;
    int rowbase = blockIdx.x * 64 + wid * 16;

    int arow = rowbase + li;
    if (arow >= N) arow = N - 1;            // clamp; invalid rows never stored
    const float* xp = x + (long)arow * FIN + g * 8;
    bf16x8 Ahi[4], Alo[4];
#pragma unroll
    for (int kb = 0; kb < 4; ++kb) {
        float4 v0 = *reinterpret_cast<const float4*>(xp + kb * 32);
        float4 v1 = *reinterpret_cast<const float4*>(xp + kb * 32 + 4);
        float vs0 = v0.x, vs1 = v0.y, vs2 = v0.z, vs3 = v0.w;
        float vs4 = v1.x, vs5 = v1.y, vs6 = v1.z, vs7 = v1.w;
        bf16x8 h8, l8;
        unsigned short hb;
        hb = f2bf_rne(vs0); h8[0] = (short)hb; l8[0] = (short)f2bf_rne(vs0 - bf2f(hb));
        hb = f2bf_rne(vs1); h8[1] = (short)hb; l8[1] = (short)f2bf_rne(vs1 - bf2f(hb));
        hb = f2bf_rne(vs2); h8[2] = (short)hb; l8[2] = (short)f2bf_rne(vs2 - bf2f(hb));
        hb = f2bf_rne(vs3); h8[3] = (short)hb; l8[3] = (short)f2bf_rne(vs3 - bf2f(hb));
        hb = f2bf_rne(vs4); h8[4] = (short)hb; l8[4] = (short)f2bf_rne(vs4 - bf2f(hb));
        hb = f2bf_rne(vs5); h8[5] = (short)hb; l8[5] = (short)f2bf_rne(vs5 - bf2f(hb));
        hb = f2bf_rne(vs6); h8[6] = (short)hb; l8[6] = (short)f2bf_rne(vs6 - bf2f(hb));
        hb = f2bf_rne(vs7); h8[7] = (short)hb; l8[7] = (short)f2bf_rne(vs7 - bf2f(hb));
        Ahi[kb] = h8; Alo[kb] = l8;
    }

    float asr[8], adr[8];
#pragma unroll
    for (int ct = 0; ct < 8; ++ct) {
        asr[ct] = a_src[ct * 16 + li];
        adr[ct] = a_dst[ct * 16 + li];
    }

    __syncthreads();

    f32x4 acc[8];
#pragma unroll
    for (int ct = 0; ct < 8; ++ct) acc[ct] = (f32x4){0.f, 0.f, 0.f, 0.f};

#pragma unroll
    for (int kb = 0; kb < 4; ++kb) {
#pragma unroll
        for (int ct = 0; ct < 8; ++ct) {
            bf16x8 bh = *reinterpret_cast<const bf16x8*>(&whi[((kb * 8 + ct) * 64 + lane) * 8]);
            bf16x8 bl = *reinterpret_cast<const bf16x8*>(&wlo[((kb * 8 + ct) * 64 + lane) * 8]);
            acc[ct] = __builtin_amdgcn_mfma_f32_16x16x32_bf16(Alo[kb], bh, acc[ct], 0, 0, 0);
            acc[ct] = __builtin_amdgcn_mfma_f32_16x16x32_bf16(Ahi[kb], bl, acc[ct], 0, 0, 0);
            acc[ct] = __builtin_amdgcn_mfma_f32_16x16x32_bf16(Ahi[kb], bh, acc[ct], 0, 0, 0);
        }
    }

    // Epilogue: store h1 (bf16) + fused per-head alpha reductions (fp32).
#pragma unroll
    for (int q = 0; q < 4; ++q) {
        int n = rowbase + g * 4 + q;
        bool valid = (n < N);
        float p0s = 0.f, p1s = 0.f, p0d = 0.f, p1d = 0.f;
#pragma unroll
        for (int ct = 0; ct < 8; ++ct) {
            float h = acc[ct][q];
            if (valid) h1b[(long)n * HC1 + ct * 16 + li] = f2bf_rne(h);
            if (ct < 4) { p0s = fmaf(h, asr[ct], p0s); p0d = fmaf(h, adr[ct], p0d); }
            else        { p1s = fmaf(h, asr[ct], p1s); p1d = fmaf(h, adr[ct], p1d); }
        }
#pragma unroll
        for (int off = 8; off >= 1; off >>= 1) {
            p0s += __shfl_xor(p0s, off, 16);
            p1s += __shfl_xor(p1s, off, 16);
            p0d += __shfl_xor(p0d, off, 16);
            p1d += __shfl_xor(p1d, off, 16);
        }
        if (valid && li == 0) {
            as1[n * 2 + 0] = p0s; as1[n * 2 + 1] = p1s;
            ad1[n * 2 + 0] = p0d; ad1[n * 2 + 1] = p1d;
        }
    }
}

// ---------------------------------------------------------------------------
// Layer 1 FUSED scores+gather: 32 lanes per node, 8 nodes per 256-block.
// Pass A: lane-strided max over edge scores (shfl width-32 reduce).
// Pass B: gather h1 rows, recomputing p on the fly (as1 is L2-resident);
// every lane accumulates the full denominator redundantly (no reduction).
// Self-loop handled analytically. No pe buffer, no barriers.
// ---------------------------------------------------------------------------
__global__ __launch_bounds__(256)
void fgather1(const int* __restrict__ eoffs, const int* __restrict__ csr,
              const float* __restrict__ as_arr, const float* __restrict__ ad_arr,
              const unsigned short* __restrict__ h1b, const float* __restrict__ b1,
              float* __restrict__ h2, int N) {
    int g = threadIdx.x >> 5;        // 0..7 node-group in block (32-lane aligned)
    int l = threadIdx.x & 31;        // lane in group: cols 4l..4l+3
    int n = blockIdx.x * 8 + g;
    if (n >= N) return;
    int head = l >> 4;
    int s0 = eoffs[n], s1 = eoffs[n + 1];

    float ad0 = ad_arr[2 * n], ad1v = ad_arr[2 * n + 1];
    float2 aself = *reinterpret_cast<const float2*>(&as_arr[2 * n]);
    float vs0 = aself.x + ad0;  vs0 = (vs0 >= 0.f) ? vs0 : NEG_SLOPE * vs0;
    float vs1 = aself.y + ad1v; vs1 = (vs1 >= 0.f) ? vs1 : NEG_SLOPE * vs1;

    // Pass A: per-head max over incoming-edge scores (self included).
    float m0 = vs0, m1 = vs1;
    for (int i = s0 + l; i < s1; i += 32) {
        float2 a = *reinterpret_cast<const float2*>(&as_arr[2 * csr[i]]);
        float v0 = a.x + ad0;  v0 = (v0 >= 0.f) ? v0 : NEG_SLOPE * v0;
        float v1 = a.y + ad1v; v1 = (v1 >= 0.f) ? v1 : NEG_SLOPE * v1;
        m0 = fmaxf(m0, v0); m1 = fmaxf(m1, v1);
    }
#pragma unroll
    for (int off = 16; off >= 1; off >>= 1) {
        m0 = fmaxf(m0, __shfl_xor(m0, off, 32));
        m1 = fmaxf(m1, __shfl_xor(m1, off, 32));
    }
    float m = head ? m1 : m0;
    float adn = head ? ad1v : ad0;

    // Pass B: gather + on-the-fly p + redundant per-lane denominator.
    float ps = __expf((head ? vs1 : vs0) - m);
    uint2 us = *reinterpret_cast<const uint2*>(&h1b[((long)n << 7) + 4 * l]);
    float4 acc;
    acc.x = bflo(us.x) * ps; acc.y = bfhi(us.x) * ps;
    acc.z = bflo(us.y) * ps; acc.w = bfhi(us.y) * ps;
    float den = ps;

    int i = s0;
    for (; i + 4 <= s1; i += 4) {
        int sa = csr[i], sb = csr[i + 1], sc = csr[i + 2], sd = csr[i + 3];
        float aa = as_arr[2 * sa + head];
        float ab = as_arr[2 * sb + head];
        float ac = as_arr[2 * sc + head];
        float ad = as_arr[2 * sd + head];
        uint2 ua = *reinterpret_cast<const uint2*>(&h1b[((long)sa << 7) + 4 * l]);
        uint2 ub = *reinterpret_cast<const uint2*>(&h1b[((long)sb << 7) + 4 * l]);
        uint2 uc = *reinterpret_cast<const uint2*>(&h1b[((long)sc << 7) + 4 * l]);
        uint2 ud = *reinterpret_cast<const uint2*>(&h1b[((long)sd << 7) + 4 * l]);
        float va = aa + adn; va = (va >= 0.f) ? va : NEG_SLOPE * va;
        float vb = ab + adn; vb = (vb >= 0.f) ? vb : NEG_SLOPE * vb;
        float vc = ac + adn; vc = (vc >= 0.f) ? vc : NEG_SLOPE * vc;
        float vd = ad + adn; vd = (vd >= 0.f) ? vd : NEG_SLOPE * vd;
        float wa = __expf(va - m);
        float wb = __expf(vb - m);
        float wc = __expf(vc - m);
        float wd = __expf(vd - m);
        den += wa + wb + wc + wd;
        acc.x = fmaf(bflo(ua.x), wa, acc.x); acc.y = fmaf(bfhi(ua.x), wa, acc.y);
        acc.z = fmaf(bflo(ua.y), wa, acc.z); acc.w = fmaf(bfhi(ua.y), wa, acc.w);
        acc.x = fmaf(bflo(ub.x), wb, acc.x); acc.y = fmaf(bfhi(ub.x), wb, acc.y);
        acc.z = fmaf(bflo(ub.y), wb, acc.z); acc.w = fmaf(bfhi(ub.y), wb, acc.w);
        acc.x = fmaf(bflo(uc.x), wc, acc.x); acc.y = fmaf(bfhi(uc.x), wc, acc.y);
        acc.z = fmaf(bflo(uc.y), wc, acc.z); acc.w = fmaf(bfhi(uc.y), wc, acc.w);
        acc.x = fmaf(bflo(ud.x), wd, acc.x); acc.y = fmaf(bfhi(ud.x), wd, acc.y);
        acc.z = fmaf(bflo(ud.y), wd, acc.z); acc.w = fmaf(bfhi(ud.y), wd, acc.w);
    }
    for (; i < s1; ++i) {
        int s = csr[i];
        float av = as_arr[2 * s + head];
        uint2 u = *reinterpret_cast<const uint2*>(&h1b[((long)s << 7) + 4 * l]);
        float v = av + adn; v = (v >= 0.f) ? v : NEG_SLOPE * v;
        float w = __expf(v - m);
        den += w;
        acc.x = fmaf(bflo(u.x), w, acc.x); acc.y = fmaf(bfhi(u.x), w, acc.y);
        acc.z = fmaf(bflo(u.y), w, acc.z); acc.w = fmaf(bfhi(u.y), w, acc.w);
    }
    float r = 1.f / (den + 1e-16f);
    int col = 4 * l;
    float4 bb = *reinterpret_cast<const float4*>(&b1[col]);
    float4 o;
    o.x = acc.x * r + bb.x; o.y = acc.y * r + bb.y;
    o.z = acc.z * r + bb.z; o.w = acc.w * r + bb.w;
    o.x = (o.x > 0.f) ? o.x : expm1f(o.x);
    o.y = (o.y > 0.f) ? o.y : expm1f(o.y);
    o.z = (o.z > 0.f) ? o.z : expm1f(o.z);
    o.w = (o.w > 0.f) ? o.w : expm1f(o.w);
    *reinterpret_cast<float4*>(&h2[((long)n << 7) + col]) = o;
}

// ---------------------------------------------------------------------------
// Layer 2 GEMM
// ---------------------------------------------------------------------------
__global__ __launch_bounds__(256)
void gemm2_alpha(const float* __restrict__ h2, const float* __restrict__ W2,
                 const float* __restrict__ a_src, const float* __restrict__ a_dst,
                 float* __restrict__ z, float* __restrict__ as2, float* __restrict__ ad2,
                 int N) {
    __shared__ float hs[16][FIN + 4];
    __shared__ float ws[FIN * NCLS];
    int tid = threadIdx.x;
    int n0 = blockIdx.x * 16;
    for (int i = tid; i < FIN * NCLS; i += 256) ws[i] = W2[i];
    for (int i = tid; i < 16 * FIN; i += 256) {
        int r = i >> 7, c = i & 127;
        int n = n0 + r;
        hs[r][c] = (n < N) ? h2[(long)n * FIN + c] : 0.f;
    }
    __syncthreads();

    int r = tid >> 4, c = tid & 15;
    int n = n0 + r;
    float acc = 0.f;
#pragma unroll 4
    for (int k = 0; k < FIN; ++k)
        acc = fmaf(hs[r][k], ws[k * NCLS + c], acc);

    float sa = acc * a_src[c];
    float da = acc * a_dst[c];
    for (int off = 8; off >= 1; off >>= 1) {
        sa += __shfl_xor(sa, off, 16);
        da += __shfl_xor(da, off, 16);
    }
    if (n < N) {
        z[n * NCLS + c] = acc;
        if (c == 0) { as2[n] = sa; ad2[n] = da; }
    }
}

// ---------------------------------------------------------------------------
// Layer 2 FUSED scores+gather + bias + log_softmax. 16 lanes per node
// (lane = class), 16 nodes per 256-block. Same two-pass structure.
// ---------------------------------------------------------------------------
__global__ __launch_bounds__(256)
void fgather2(const int* __restrict__ eoffs, const int* __restrict__ csr,
              const float* __restrict__ as2, const float* __restrict__ ad2,
              const float* __restrict__ z, const float* __restrict__ b2,
              float* __restrict__ out, int N) {
    int g = threadIdx.x >> 4;
    int l = threadIdx.x & 15;
    int n = blockIdx.x * 16 + g;
    if (n >= N) return;
    int s0 = eoffs[n], s1 = eoffs[n + 1];
    float adn = ad2[n];
    float vs = as2[n] + adn; vs = (vs >= 0.f) ? vs : NEG_SLOPE * vs;

    // Pass A: max over scores (self included).
    float m = vs;
    for (int i = s0 + l; i < s1; i += 16) {
        float v = as2[csr[i]] + adn;
        v = (v >= 0.f) ? v : NEG_SLOPE * v;
        m = fmaxf(m, v);
    }
#pragma unroll
    for (int off = 8; off >= 1; off >>= 1) m = fmaxf(m, __shfl_xor(m, off, 16));

    // Pass B: gather + on-the-fly p + redundant denominator.
    float ps = __expf(vs - m);
    float acc = ps * z[(long)n * NCLS + l];
    float den = ps;
    int i = s0;
    for (; i + 4 <= s1; i += 4) {
        int sa = csr[i], sb = csr[i + 1], sc = csr[i + 2], sd = csr[i + 3];
        float aa = as2[sa], ab = as2[sb], ac = as2[sc], ad = as2[sd];
        float za = z[sa * NCLS + l];
        float zb = z[sb * NCLS + l];
        float zc = z[sc * NCLS + l];
        float zd = z[sd * NCLS + l];
        float va = aa + adn; va = (va >= 0.f) ? va : NEG_SLOPE * va;
        float vb = ab + adn; vb = (vb >= 0.f) ? vb : NEG_SLOPE * vb;
        float vc = ac + adn; vc = (vc >= 0.f) ? vc : NEG_SLOPE * vc;
        float vd = ad + adn; vd = (vd >= 0.f) ? vd : NEG_SLOPE * vd;
        float pa = __expf(va - m);
        float pb = __expf(vb - m);
        float pc = __expf(vc - m);
        float pd = __expf(vd - m);
        den += pa + pb + pc + pd;
        acc = fmaf(za, pa, acc);
        acc = fmaf(zb, pb, acc);
        acc = fmaf(zc, pc, acc);
        acc = fmaf(zd, pd, acc);
    }
    for (; i < s1; ++i) {
        int s = csr[i];
        float v = as2[s] + adn; v = (v >= 0.f) ? v : NEG_SLOPE * v;
        float p = __expf(v - m);
        den += p;
        acc = fmaf(z[s * NCLS + l], p, acc);
    }

    float o = acc / (den + 1e-16f) + b2[l];

    float mx = o;
#pragma unroll
    for (int off = 8; off >= 1; off >>= 1) mx = fmaxf(mx, __shfl_xor(mx, off, 16));
    float ex = __expf(o - mx);
    float sum = ex;
#pragma unroll
    for (int off = 8; off >= 1; off >>= 1) sum += __shfl_xor(sum, off, 16);
    out[(long)n * NCLS + l] = o - mx - __logf(sum);
}

// ---------------------------------------------------------------------------
extern "C" void kernel_launch(void* const* d_in, const int* in_sizes, int n_in,
                              void* d_out, int out_size, void* d_ws, size_t ws_size,
                              hipStream_t stream) {
    const float* x        = (const float*)d_in[0];
    const int*   ei       = (const int*)  d_in[1];
    // d_in[2] = edge_attr (unused by reference)
    const float* W1       = (const float*)d_in[3];
    const float* att_src1 = (const float*)d_in[4];
    const float* att_dst1 = (const float*)d_in[5];
    const float* b1       = (const float*)d_in[6];
    const float* W2       = (const float*)d_in[7];
    const float* att_src2 = (const float*)d_in[8];
    const float* att_dst2 = (const float*)d_in[9];
    const float* b2       = (const float*)d_in[10];
    float* out = (float*)d_out;

    const int N = in_sizes[0] / FIN;        // 50000
    const int E = in_sizes[1] / 2;          // 800000
    const int NB = (N + 255) >> 8;          // 196 buckets
    const int EB = (E + EPB - 1) / EPB;     // 196 edge blocks (<=256)

    // Workspace layout (bytes), with aliasing for layer-2 temporaries
    char* ws = (char*)d_ws;
    size_t off = 0;
    auto alloc = [&](size_t bytes) { char* p = ws + off; off += (bytes + 255) & ~(size_t)255; return p; };
    int*    blockhist     = (int*)  alloc((size_t)EB * NB * 4);
    int*    colsum        = (int*)  alloc((size_t)NB * 4);
    int*    bucket_base   = (int*)  alloc((size_t)(NB + 1) * 4);
    int2*   tmp           = (int2*) alloc((size_t)E * 8);
    int*    csr           = (int*)  alloc((size_t)E * 4);
    int*    eoffs         = (int*)  alloc((size_t)(N + 1) * 4);
    unsigned short* h1b   = (unsigned short*)alloc((size_t)N * HC1 * 2);  // bf16
    float*  h2            = (float*) alloc((size_t)N * HC1 * 4);
    float*  z             = (float*) alloc((size_t)N * NCLS * 4);
    float*  as1           = (float*) alloc((size_t)N * 2 * 4); // layer2: as2 aliases
    float*  ad1           = (float*) alloc((size_t)N * 2 * 4); // layer2: ad2 aliases
    (void)ws_size;

    float* as2 = as1;
    float* ad2 = ad1;

    bcnt_kernel<<<EB, 256, 0, stream>>>(ei, blockhist, E, NB);
    colscan_kernel<<<NB, 256, 0, stream>>>(blockhist, colsum, EB, NB);
    bscan2_kernel<<<1, 256, 0, stream>>>(colsum, bucket_base, NB);
    binA_kernel<<<EB, 256, 0, stream>>>(ei, blockhist, bucket_base, tmp, E, NB);
    binB_kernel<<<NB, 256, 0, stream>>>(tmp, bucket_base, csr, eoffs, E, N);

    gemm1_mfma<<<(N + 63) / 64, 256, 0, stream>>>(
        x, W1, att_src1, att_dst1, h1b, as1, ad1, N);
    fgather1<<<(N + 7) / 8, 256, 0, stream>>>(eoffs, csr, as1, ad1, h1b, b1, h2, N);

    gemm2_alpha<<<(N + 15) / 16, 256, 0, stream>>>(
        h2, W2, att_src2, att_dst2, z, as2, ad2, N);
    fgather2<<<(N + 15) / 16, 256, 0, stream>>>(eoffs, csr, as2, ad2, z, b2, out, N);
}

// Round 12
// 130.585 us; speedup vs baseline: 1.6142x; 1.0292x over previous
//
#include <hip/hip_runtime.h>
#include <math.h>

// Problem constants (match reference)
#define FIN   128
#define HC1   128   // H*C for layer 1
#define NCLS  16
#define NEG_SLOPE 0.2f

typedef __attribute__((ext_vector_type(8))) short bf16x8;
typedef __attribute__((ext_vector_type(4))) float f32x4;

__device__ __forceinline__ unsigned short f2bf_rne(float f) {
    unsigned int u = __float_as_uint(f);
    unsigned int r = u + 0x7FFFu + ((u >> 16) & 1u);
    return (unsigned short)(r >> 16);
}
__device__ __forceinline__ float bf2f(unsigned short h) {
    return __uint_as_float(((unsigned int)h) << 16);
}
__device__ __forceinline__ float bflo(unsigned int u) { return __uint_as_float(u << 16); }
__device__ __forceinline__ float bfhi(unsigned int u) { return __uint_as_float(u & 0xFFFF0000u); }

// ---------------------------------------------------------------------------
// CSR build via two-level bucket sort (bucket = dst>>8). Memset-free,
// global-atomic-free. Self-loops are NOT in the CSR (handled analytically).
// ---------------------------------------------------------------------------
#define EPB 4096   // edges per block in bcnt/binA  (EB = ceil(E/EPB) must be <=256)

__global__ __launch_bounds__(256)
void bcnt_kernel(const int* __restrict__ ei, int* __restrict__ blockhist,
                 int E, int NB) {
    __shared__ int h[256];
    int tid = threadIdx.x;
    h[tid] = 0;
    __syncthreads();
    int base = blockIdx.x * EPB;
#pragma unroll
    for (int j = 0; j < EPB / 256; ++j) {
        int e = base + j * 256 + tid;
        if (e < E) atomicAdd(&h[ei[E + e] >> 8], 1);
    }
    __syncthreads();
    if (tid < NB) blockhist[blockIdx.x * NB + tid] = h[tid];
}

// NB blocks; block t scans its COLUMN of blockhist (one element/thread).
__global__ __launch_bounds__(256)
void colscan_kernel(int* __restrict__ blockhist, int* __restrict__ colsum,
                    int EB, int NB) {
    __shared__ int lds[256];
    int t = blockIdx.x;       // bucket (column)
    int b = threadIdx.x;      // edge-block (row)
    int v = (b < EB) ? blockhist[b * NB + t] : 0;
    lds[b] = v;
    __syncthreads();
    for (int off = 1; off < 256; off <<= 1) {
        int u = (b >= off) ? lds[b - off] : 0;
        __syncthreads();
        lds[b] += u;
        __syncthreads();
    }
    if (b < EB) blockhist[b * NB + t] = lds[b] - v;   // excl offset within bucket
    if (b == 255) colsum[t] = lds[255];
}

// 1 block: exclusive scan of colsum -> bucket_base[0..NB].
__global__ __launch_bounds__(256)
void bscan2_kernel(const int* __restrict__ colsum, int* __restrict__ bucket_base,
                   int NB) {
    __shared__ int lds[256];
    int t = threadIdx.x;
    int v = (t < NB) ? colsum[t] : 0;
    lds[t] = v;
    __syncthreads();
    for (int off = 1; off < 256; off <<= 1) {
        int u = (t >= off) ? lds[t - off] : 0;
        __syncthreads();
        lds[t] += u;
        __syncthreads();
    }
    if (t < NB) bucket_base[t] = lds[t] - v;
    if (t == 255) bucket_base[NB] = lds[255];   // == E
}

__global__ __launch_bounds__(256)
void binA_kernel(const int* __restrict__ ei, const int* __restrict__ blockhist,
                 const int* __restrict__ bucket_base,
                 int2* __restrict__ tmp, int E, int NB) {
    __shared__ int h[256];    // local cursors
    __shared__ int bb[256];   // this block's global base per bucket
    int tid = threadIdx.x;
    h[tid] = 0;
    if (tid < NB) bb[tid] = blockhist[blockIdx.x * NB + tid] + bucket_base[tid];
    __syncthreads();
    int base = blockIdx.x * EPB;
#pragma unroll
    for (int j = 0; j < EPB / 256; ++j) {
        int e = base + j * 256 + tid;
        if (e < E) {
            int s = ei[e], d = ei[E + e];
            int b = d >> 8;
            int r = atomicAdd(&h[b], 1);
            tmp[bb[b] + r] = make_int2(s, d);
        }
    }
}

// One block per bucket: sorts its bucket by node, writes csr densely and
// emits eoffs (global CSR offsets) directly.
__global__ __launch_bounds__(256)
void binB_kernel(const int2* __restrict__ tmp, const int* __restrict__ bucket_base,
                 int* __restrict__ csr, int* __restrict__ eoffs, int E, int N) {
    __shared__ int cnt[256];
    __shared__ int lds[256];
    __shared__ int cur[256];
    int b = blockIdx.x, t = threadIdx.x;
    int lo = bucket_base[b], hi = bucket_base[b + 1];
    cnt[t] = 0;
    __syncthreads();
    for (int i = lo + t; i < hi; i += 256)
        atomicAdd(&cnt[tmp[i].y & 255], 1);
    __syncthreads();
    int v = cnt[t];
    lds[t] = v;
    __syncthreads();
    for (int off = 1; off < 256; off <<= 1) {
        int u = (t >= off) ? lds[t - off] : 0;
        __syncthreads();
        lds[t] += u;
        __syncthreads();
    }
    int excl = lds[t] - v;
    int node = b * 256 + t;
    if (node < N) eoffs[node] = lo + excl;
    if (b == 0 && t == 0) eoffs[N] = E;
    cur[t] = lo + excl;
    __syncthreads();
    for (int i = lo + t; i < hi; i += 256) {
        int2 e = tmp[i];
        int p = atomicAdd(&cur[e.y & 255], 1);
        csr[p] = e.x;
    }
}

// ---------------------------------------------------------------------------
// Layer 1 GEMM via split-bf16 MFMA: h1 = x @ W1, ~fp32 accuracy.
// h1 stored bf16; alpha scalars from full fp32 accumulator.
// ---------------------------------------------------------------------------
__global__ __launch_bounds__(256)
void gemm1_mfma(const float* __restrict__ x, const float* __restrict__ W,
                const float* __restrict__ a_src, const float* __restrict__ a_dst,
                unsigned short* __restrict__ h1b, float* __restrict__ as1,
                float* __restrict__ ad1, int N) {
    __shared__ unsigned short whi[FIN * HC1];   // 32 KB, fragment-ordered
    __shared__ unsigned short wlo[FIN * HC1];   // 32 KB
    int tid = threadIdx.x;

#pragma unroll
    for (int i = 0; i < 64; ++i) {
        int idx = tid + i * 256;            // 0..16383, coalesced
        int k = idx >> 7, c = idx & 127;
        float v = W[idx];
        unsigned short hb = f2bf_rne(v);
        unsigned short lb = f2bf_rne(v - bf2f(hb));
        int kb = k >> 5, kk = k & 31;
        int g = kk >> 3, j = kk & 7;
        int ct = c >> 4, li = c & 15;
        int off = ((kb * 8 + ct) * 64 + g * 16 + li) * 8 + j;
        whi[off] = hb;
        wlo[off] = lb;
    }

    int wid = tid >> 6, lane = tid & 63;
    int li = lane & 15, g = lane >> 4;
    int rowbase = blockIdx.x * 64 + wid * 16;

    int arow = rowbase + li;
    if (arow >= N) arow = N - 1;            // clamp; invalid rows never stored
    const float* xp = x + (long)arow * FIN + g * 8;
    bf16x8 Ahi[4], Alo[4];
#pragma unroll
    for (int kb = 0; kb < 4; ++kb) {
        float4 v0 = *reinterpret_cast<const float4*>(xp + kb * 32);
        float4 v1 = *reinterpret_cast<const float4*>(xp + kb * 32 + 4);
        float vs0 = v0.x, vs1 = v0.y, vs2 = v0.z, vs3 = v0.w;
        float vs4 = v1.x, vs5 = v1.y, vs6 = v1.z, vs7 = v1.w;
        bf16x8 h8, l8;
        unsigned short hb;
        hb = f2bf_rne(vs0); h8[0] = (short)hb; l8[0] = (short)f2bf_rne(vs0 - bf2f(hb));
        hb = f2bf_rne(vs1); h8[1] = (short)hb; l8[1] = (short)f2bf_rne(vs1 - bf2f(hb));
        hb = f2bf_rne(vs2); h8[2] = (short)hb; l8[2] = (short)f2bf_rne(vs2 - bf2f(hb));
        hb = f2bf_rne(vs3); h8[3] = (short)hb; l8[3] = (short)f2bf_rne(vs3 - bf2f(hb));
        hb = f2bf_rne(vs4); h8[4] = (short)hb; l8[4] = (short)f2bf_rne(vs4 - bf2f(hb));
        hb = f2bf_rne(vs5); h8[5] = (short)hb; l8[5] = (short)f2bf_rne(vs5 - bf2f(hb));
        hb = f2bf_rne(vs6); h8[6] = (short)hb; l8[6] = (short)f2bf_rne(vs6 - bf2f(hb));
        hb = f2bf_rne(vs7); h8[7] = (short)hb; l8[7] = (short)f2bf_rne(vs7 - bf2f(hb));
        Ahi[kb] = h8; Alo[kb] = l8;
    }

    float asr[8], adr[8];
#pragma unroll
    for (int ct = 0; ct < 8; ++ct) {
        asr[ct] = a_src[ct * 16 + li];
        adr[ct] = a_dst[ct * 16 + li];
    }

    __syncthreads();

    f32x4 acc[8];
#pragma unroll
    for (int ct = 0; ct < 8; ++ct) acc[ct] = (f32x4){0.f, 0.f, 0.f, 0.f};

#pragma unroll
    for (int kb = 0; kb < 4; ++kb) {
#pragma unroll
        for (int ct = 0; ct < 8; ++ct) {
            bf16x8 bh = *reinterpret_cast<const bf16x8*>(&whi[((kb * 8 + ct) * 64 + lane) * 8]);
            bf16x8 bl = *reinterpret_cast<const bf16x8*>(&wlo[((kb * 8 + ct) * 64 + lane) * 8]);
            acc[ct] = __builtin_amdgcn_mfma_f32_16x16x32_bf16(Alo[kb], bh, acc[ct], 0, 0, 0);
            acc[ct] = __builtin_amdgcn_mfma_f32_16x16x32_bf16(Ahi[kb], bl, acc[ct], 0, 0, 0);
            acc[ct] = __builtin_amdgcn_mfma_f32_16x16x32_bf16(Ahi[kb], bh, acc[ct], 0, 0, 0);
        }
    }

    // Epilogue: store h1 (bf16) + fused per-head alpha reductions (fp32).
#pragma unroll
    for (int q = 0; q < 4; ++q) {
        int n = rowbase + g * 4 + q;
        bool valid = (n < N);
        float p0s = 0.f, p1s = 0.f, p0d = 0.f, p1d = 0.f;
#pragma unroll
        for (int ct = 0; ct < 8; ++ct) {
            float h = acc[ct][q];
            if (valid) h1b[(long)n * HC1 + ct * 16 + li] = f2bf_rne(h);
            if (ct < 4) { p0s = fmaf(h, asr[ct], p0s); p0d = fmaf(h, adr[ct], p0d); }
            else        { p1s = fmaf(h, asr[ct], p1s); p1d = fmaf(h, adr[ct], p1d); }
        }
#pragma unroll
        for (int off = 8; off >= 1; off >>= 1) {
            p0s += __shfl_xor(p0s, off, 16);
            p1s += __shfl_xor(p1s, off, 16);
            p0d += __shfl_xor(p0d, off, 16);
            p1d += __shfl_xor(p1d, off, 16);
        }
        if (valid && li == 0) {
            as1[n * 2 + 0] = p0s; as1[n * 2 + 1] = p1s;
            ad1[n * 2 + 0] = p0d; ad1[n * 2 + 1] = p1d;
        }
    }
}

// ---------------------------------------------------------------------------
// Layer 1 FUSED scores+gather+ELU+GEMM2+alpha2: 32 lanes per node,
// 8 nodes per 256-block. After the softmax-weighted gather and ELU, the
// 32 lanes (holding the 128-value h2 row) compute z = h2 @ W2 in-register
// (W2 transposed in LDS), butterfly-reduce, and lane 0 writes z + as2/ad2.
// h2 is never materialized. Requires grid*8 == N exactly (barrier safety).
// ---------------------------------------------------------------------------
__global__ __launch_bounds__(256)
void fgather1(const int* __restrict__ eoffs, const int* __restrict__ csr,
              const float* __restrict__ as_arr, const float* __restrict__ ad_arr,
              const unsigned short* __restrict__ h1b, const float* __restrict__ b1,
              const float* __restrict__ W2,
              const float* __restrict__ a_src2, const float* __restrict__ a_dst2,
              float* __restrict__ zout, float* __restrict__ as2,
              float* __restrict__ ad2, int N) {
    __shared__ float wsT[NCLS * FIN];   // 8 KB, W2 transposed: wsT[c*128+k]
    int tid = threadIdx.x;
    if (tid < 128) {
#pragma unroll
        for (int c = 0; c < NCLS; ++c) wsT[c * FIN + tid] = W2[tid * NCLS + c];
    }
    __syncthreads();

    int g = tid >> 5;                // 0..7 node-group in block (32-lane aligned)
    int l = tid & 31;                // lane in group: cols 4l..4l+3
    int n = blockIdx.x * 8 + g;
    if (n >= N) return;
    int head = l >> 4;
    int s0 = eoffs[n], s1 = eoffs[n + 1];

    float ad0 = ad_arr[2 * n], ad1v = ad_arr[2 * n + 1];
    float2 aself = *reinterpret_cast<const float2*>(&as_arr[2 * n]);
    float vs0 = aself.x + ad0;  vs0 = (vs0 >= 0.f) ? vs0 : NEG_SLOPE * vs0;
    float vs1 = aself.y + ad1v; vs1 = (vs1 >= 0.f) ? vs1 : NEG_SLOPE * vs1;

    // Pass A: per-head max over incoming-edge scores (self included).
    float m0 = vs0, m1 = vs1;
    for (int i = s0 + l; i < s1; i += 32) {
        float2 a = *reinterpret_cast<const float2*>(&as_arr[2 * csr[i]]);
        float v0 = a.x + ad0;  v0 = (v0 >= 0.f) ? v0 : NEG_SLOPE * v0;
        float v1 = a.y + ad1v; v1 = (v1 >= 0.f) ? v1 : NEG_SLOPE * v1;
        m0 = fmaxf(m0, v0); m1 = fmaxf(m1, v1);
    }
#pragma unroll
    for (int off = 16; off >= 1; off >>= 1) {
        m0 = fmaxf(m0, __shfl_xor(m0, off, 32));
        m1 = fmaxf(m1, __shfl_xor(m1, off, 32));
    }
    float m = head ? m1 : m0;
    float adn = head ? ad1v : ad0;

    // Pass B: gather + on-the-fly p + redundant per-lane denominator.
    float ps = __expf((head ? vs1 : vs0) - m);
    uint2 us = *reinterpret_cast<const uint2*>(&h1b[((long)n << 7) + 4 * l]);
    float4 acc;
    acc.x = bflo(us.x) * ps; acc.y = bfhi(us.x) * ps;
    acc.z = bflo(us.y) * ps; acc.w = bfhi(us.y) * ps;
    float den = ps;

    int i = s0;
    for (; i + 4 <= s1; i += 4) {
        int sa = csr[i], sb = csr[i + 1], sc = csr[i + 2], sd = csr[i + 3];
        float aa = as_arr[2 * sa + head];
        float ab = as_arr[2 * sb + head];
        float ac = as_arr[2 * sc + head];
        float ad = as_arr[2 * sd + head];
        uint2 ua = *reinterpret_cast<const uint2*>(&h1b[((long)sa << 7) + 4 * l]);
        uint2 ub = *reinterpret_cast<const uint2*>(&h1b[((long)sb << 7) + 4 * l]);
        uint2 uc = *reinterpret_cast<const uint2*>(&h1b[((long)sc << 7) + 4 * l]);
        uint2 ud = *reinterpret_cast<const uint2*>(&h1b[((long)sd << 7) + 4 * l]);
        float va = aa + adn; va = (va >= 0.f) ? va : NEG_SLOPE * va;
        float vb = ab + adn; vb = (vb >= 0.f) ? vb : NEG_SLOPE * vb;
        float vc = ac + adn; vc = (vc >= 0.f) ? vc : NEG_SLOPE * vc;
        float vd = ad + adn; vd = (vd >= 0.f) ? vd : NEG_SLOPE * vd;
        float wa = __expf(va - m);
        float wb = __expf(vb - m);
        float wc = __expf(vc - m);
        float wd = __expf(vd - m);
        den += wa + wb + wc + wd;
        acc.x = fmaf(bflo(ua.x), wa, acc.x); acc.y = fmaf(bfhi(ua.x), wa, acc.y);
        acc.z = fmaf(bflo(ua.y), wa, acc.z); acc.w = fmaf(bfhi(ua.y), wa, acc.w);
        acc.x = fmaf(bflo(ub.x), wb, acc.x); acc.y = fmaf(bfhi(ub.x), wb, acc.y);
        acc.z = fmaf(bflo(ub.y), wb, acc.z); acc.w = fmaf(bfhi(ub.y), wb, acc.w);
        acc.x = fmaf(bflo(uc.x), wc, acc.x); acc.y = fmaf(bfhi(uc.x), wc, acc.y);
        acc.z = fmaf(bflo(uc.y), wc, acc.z); acc.w = fmaf(bfhi(uc.y), wc, acc.w);
        acc.x = fmaf(bflo(ud.x), wd, acc.x); acc.y = fmaf(bfhi(ud.x), wd, acc.y);
        acc.z = fmaf(bflo(ud.y), wd, acc.z); acc.w = fmaf(bfhi(ud.y), wd, acc.w);
    }
    for (; i < s1; ++i) {
        int s = csr[i];
        float av = as_arr[2 * s + head];
        uint2 u = *reinterpret_cast<const uint2*>(&h1b[((long)s << 7) + 4 * l]);
        float v = av + adn; v = (v >= 0.f) ? v : NEG_SLOPE * v;
        float w = __expf(v - m);
        den += w;
        acc.x = fmaf(bflo(u.x), w, acc.x); acc.y = fmaf(bfhi(u.x), w, acc.y);
        acc.z = fmaf(bflo(u.y), w, acc.z); acc.w = fmaf(bfhi(u.y), w, acc.w);
    }
    float r = 1.f / (den + 1e-16f);
    int col = 4 * l;
    float4 bb = *reinterpret_cast<const float4*>(&b1[col]);
    float4 o;
    o.x = acc.x * r + bb.x; o.y = acc.y * r + bb.y;
    o.z = acc.z * r + bb.z; o.w = acc.w * r + bb.w;
    o.x = (o.x > 0.f) ? o.x : expm1f(o.x);
    o.y = (o.y > 0.f) ? o.y : expm1f(o.y);
    o.z = (o.z > 0.f) ? o.z : expm1f(o.z);
    o.w = (o.w > 0.f) ? o.w : expm1f(o.w);

    // Fused GEMM2: z[c] = sum_k h2[k] * W2[k][c]; this lane holds k=col..col+3.
    float zp[NCLS];
#pragma unroll
    for (int c = 0; c < NCLS; ++c) {
        const float* wc = &wsT[c * FIN + col];
        zp[c] = o.x * wc[0] + o.y * wc[1] + o.z * wc[2] + o.w * wc[3];
    }
#pragma unroll
    for (int off = 16; off >= 1; off >>= 1) {
#pragma unroll
        for (int c = 0; c < NCLS; ++c) zp[c] += __shfl_xor(zp[c], off, 32);
    }
    if (l == 0) {
        float sa = 0.f, da = 0.f;
#pragma unroll
        for (int c = 0; c < NCLS; ++c) {
            sa = fmaf(zp[c], a_src2[c], sa);
            da = fmaf(zp[c], a_dst2[c], da);
        }
        as2[n] = sa; ad2[n] = da;
        float* zr = &zout[(long)n * NCLS];
        *reinterpret_cast<float4*>(zr + 0)  = make_float4(zp[0],  zp[1],  zp[2],  zp[3]);
        *reinterpret_cast<float4*>(zr + 4)  = make_float4(zp[4],  zp[5],  zp[6],  zp[7]);
        *reinterpret_cast<float4*>(zr + 8)  = make_float4(zp[8],  zp[9],  zp[10], zp[11]);
        *reinterpret_cast<float4*>(zr + 12) = make_float4(zp[12], zp[13], zp[14], zp[15]);
    }
}

// ---------------------------------------------------------------------------
// Layer 2 FUSED scores+gather + bias + log_softmax. 16 lanes per node
// (lane = class), 16 nodes per 256-block.
// ---------------------------------------------------------------------------
__global__ __launch_bounds__(256)
void fgather2(const int* __restrict__ eoffs, const int* __restrict__ csr,
              const float* __restrict__ as2, const float* __restrict__ ad2,
              const float* __restrict__ z, const float* __restrict__ b2,
              float* __restrict__ out, int N) {
    int g = threadIdx.x >> 4;
    int l = threadIdx.x & 15;
    int n = blockIdx.x * 16 + g;
    if (n >= N) return;
    int s0 = eoffs[n], s1 = eoffs[n + 1];
    float adn = ad2[n];
    float vs = as2[n] + adn; vs = (vs >= 0.f) ? vs : NEG_SLOPE * vs;

    // Pass A: max over scores (self included).
    float m = vs;
    for (int i = s0 + l; i < s1; i += 16) {
        float v = as2[csr[i]] + adn;
        v = (v >= 0.f) ? v : NEG_SLOPE * v;
        m = fmaxf(m, v);
    }
#pragma unroll
    for (int off = 8; off >= 1; off >>= 1) m = fmaxf(m, __shfl_xor(m, off, 16));

    // Pass B: gather + on-the-fly p + redundant denominator.
    float ps = __expf(vs - m);
    float acc = ps * z[(long)n * NCLS + l];
    float den = ps;
    int i = s0;
    for (; i + 4 <= s1; i += 4) {
        int sa = csr[i], sb = csr[i + 1], sc = csr[i + 2], sd = csr[i + 3];
        float aa = as2[sa], ab = as2[sb], ac = as2[sc], ad = as2[sd];
        float za = z[sa * NCLS + l];
        float zb = z[sb * NCLS + l];
        float zc = z[sc * NCLS + l];
        float zd = z[sd * NCLS + l];
        float va = aa + adn; va = (va >= 0.f) ? va : NEG_SLOPE * va;
        float vb = ab + adn; vb = (vb >= 0.f) ? vb : NEG_SLOPE * vb;
        float vc = ac + adn; vc = (vc >= 0.f) ? vc : NEG_SLOPE * vc;
        float vd = ad + adn; vd = (vd >= 0.f) ? vd : NEG_SLOPE * vd;
        float pa = __expf(va - m);
        float pb = __expf(vb - m);
        float pc = __expf(vc - m);
        float pd = __expf(vd - m);
        den += pa + pb + pc + pd;
        acc = fmaf(za, pa, acc);
        acc = fmaf(zb, pb, acc);
        acc = fmaf(zc, pc, acc);
        acc = fmaf(zd, pd, acc);
    }
    for (; i < s1; ++i) {
        int s = csr[i];
        float v = as2[s] + adn; v = (v >= 0.f) ? v : NEG_SLOPE * v;
        float p = __expf(v - m);
        den += p;
        acc = fmaf(z[s * NCLS + l], p, acc);
    }

    float o = acc / (den + 1e-16f) + b2[l];

    float mx = o;
#pragma unroll
    for (int off = 8; off >= 1; off >>= 1) mx = fmaxf(mx, __shfl_xor(mx, off, 16));
    float ex = __expf(o - mx);
    float sum = ex;
#pragma unroll
    for (int off = 8; off >= 1; off >>= 1) sum += __shfl_xor(sum, off, 16);
    out[(long)n * NCLS + l] = o - mx - __logf(sum);
}

// ---------------------------------------------------------------------------
extern "C" void kernel_launch(void* const* d_in, const int* in_sizes, int n_in,
                              void* d_out, int out_size, void* d_ws, size_t ws_size,
                              hipStream_t stream) {
    const float* x        = (const float*)d_in[0];
    const int*   ei       = (const int*)  d_in[1];
    // d_in[2] = edge_attr (unused by reference)
    const float* W1       = (const float*)d_in[3];
    const float* att_src1 = (const float*)d_in[4];
    const float* att_dst1 = (const float*)d_in[5];
    const float* b1       = (const float*)d_in[6];
    const float* W2       = (const float*)d_in[7];
    const float* att_src2 = (const float*)d_in[8];
    const float* att_dst2 = (const float*)d_in[9];
    const float* b2       = (const float*)d_in[10];
    float* out = (float*)d_out;

    const int N = in_sizes[0] / FIN;        // 50000
    const int E = in_sizes[1] / 2;          // 800000
    const int NB = (N + 255) >> 8;          // 196 buckets
    const int EB = (E + EPB - 1) / EPB;     // 196 edge blocks (<=256)

    // Workspace layout (bytes)
    char* ws = (char*)d_ws;
    size_t off = 0;
    auto alloc = [&](size_t bytes) { char* p = ws + off; off += (bytes + 255) & ~(size_t)255; return p; };
    int*    blockhist     = (int*)  alloc((size_t)EB * NB * 4);
    int*    colsum        = (int*)  alloc((size_t)NB * 4);
    int*    bucket_base   = (int*)  alloc((size_t)(NB + 1) * 4);
    int2*   tmp           = (int2*) alloc((size_t)E * 8);
    int*    csr           = (int*)  alloc((size_t)E * 4);
    int*    eoffs         = (int*)  alloc((size_t)(N + 1) * 4);
    unsigned short* h1b   = (unsigned short*)alloc((size_t)N * HC1 * 2);  // bf16
    float*  z             = (float*) alloc((size_t)N * NCLS * 4);
    float*  as1           = (float*) alloc((size_t)N * 2 * 4);
    float*  ad1           = (float*) alloc((size_t)N * 2 * 4);
    float*  as2           = (float*) alloc((size_t)N * 4);   // distinct: fgather1
    float*  ad2           = (float*) alloc((size_t)N * 4);   // reads as1/ad1 live
    (void)ws_size;

    bcnt_kernel<<<EB, 256, 0, stream>>>(ei, blockhist, E, NB);
    colscan_kernel<<<NB, 256, 0, stream>>>(blockhist, colsum, EB, NB);
    bscan2_kernel<<<1, 256, 0, stream>>>(colsum, bucket_base, NB);
    binA_kernel<<<EB, 256, 0, stream>>>(ei, blockhist, bucket_base, tmp, E, NB);
    binB_kernel<<<NB, 256, 0, stream>>>(tmp, bucket_base, csr, eoffs, E, N);

    gemm1_mfma<<<(N + 63) / 64, 256, 0, stream>>>(
        x, W1, att_src1, att_dst1, h1b, as1, ad1, N);
    fgather1<<<(N + 7) / 8, 256, 0, stream>>>(
        eoffs, csr, as1, ad1, h1b, b1, W2, att_src2, att_dst2, z, as2, ad2, N);
    fgather2<<<(N + 15) / 16, 256, 0, stream>>>(eoffs, csr, as2, ad2, z, b2, out, N);
}

// Round 13
// 124.982 us; speedup vs baseline: 1.6865x; 1.0448x over previous
//
#include <hip/hip_runtime.h>
#include <math.h>

// Problem constants (match reference)
#define FIN   128
#define HC1   128   // H*C for layer 1
#define NCLS  16
#define NEG_SLOPE 0.2f

typedef __attribute__((ext_vector_type(8))) short bf16x8;
typedef __attribute__((ext_vector_type(4))) float f32x4;

__device__ __forceinline__ unsigned short f2bf_rne(float f) {
    unsigned int u = __float_as_uint(f);
    unsigned int r = u + 0x7FFFu + ((u >> 16) & 1u);
    return (unsigned short)(r >> 16);
}
__device__ __forceinline__ float bf2f(unsigned short h) {
    return __uint_as_float(((unsigned int)h) << 16);
}
__device__ __forceinline__ float bflo(unsigned int u) { return __uint_as_float(u << 16); }
__device__ __forceinline__ float bfhi(unsigned int u) { return __uint_as_float(u & 0xFFFF0000u); }

// ---------------------------------------------------------------------------
// CSR build via two-level bucket sort (bucket = dst>>8). Memset-free,
// global-atomic-free. Self-loops are NOT in the CSR (handled analytically).
// ---------------------------------------------------------------------------
#define EPB 4096   // edges per block in bcnt/binA  (EB = ceil(E/EPB) must be <=256)

__global__ __launch_bounds__(256)
void bcnt_kernel(const int* __restrict__ ei, int* __restrict__ blockhist,
                 int E, int NB) {
    __shared__ int h[256];
    int tid = threadIdx.x;
    h[tid] = 0;
    __syncthreads();
    int base = blockIdx.x * EPB;
#pragma unroll
    for (int j = 0; j < EPB / 256; ++j) {
        int e = base + j * 256 + tid;
        if (e < E) atomicAdd(&h[ei[E + e] >> 8], 1);
    }
    __syncthreads();
    if (tid < NB) blockhist[blockIdx.x * NB + tid] = h[tid];
}

// NB blocks; block t scans its COLUMN of blockhist (one element/thread).
__global__ __launch_bounds__(256)
void colscan_kernel(int* __restrict__ blockhist, int* __restrict__ colsum,
                    int EB, int NB) {
    __shared__ int lds[256];
    int t = blockIdx.x;       // bucket (column)
    int b = threadIdx.x;      // edge-block (row)
    int v = (b < EB) ? blockhist[b * NB + t] : 0;
    lds[b] = v;
    __syncthreads();
    for (int off = 1; off < 256; off <<= 1) {
        int u = (b >= off) ? lds[b - off] : 0;
        __syncthreads();
        lds[b] += u;
        __syncthreads();
    }
    if (b < EB) blockhist[b * NB + t] = lds[b] - v;   // excl offset within bucket
    if (b == 255) colsum[t] = lds[255];
}

// 1 block: exclusive scan of colsum -> bucket_base[0..NB].
// Also preps W2 transpose + alpha2 projections (independent tiny work).
__global__ __launch_bounds__(256)
void bscan2_kernel(const int* __restrict__ colsum, int* __restrict__ bucket_base,
                   int NB, const float* __restrict__ W2,
                   const float* __restrict__ a_src2, const float* __restrict__ a_dst2,
                   float* __restrict__ w2T, float* __restrict__ w2s,
                   float* __restrict__ w2d) {
    __shared__ int lds[256];
    int t = threadIdx.x;
    int v = (t < NB) ? colsum[t] : 0;
    lds[t] = v;
    __syncthreads();
    for (int off = 1; off < 256; off <<= 1) {
        int u = (t >= off) ? lds[t - off] : 0;
        __syncthreads();
        lds[t] += u;
        __syncthreads();
    }
    if (t < NB) bucket_base[t] = lds[t] - v;
    if (t == 255) bucket_base[NB] = lds[255];   // == E

    if (t < FIN) {
        float s = 0.f, d = 0.f;
#pragma unroll
        for (int c = 0; c < NCLS; ++c) {
            float w = W2[t * NCLS + c];
            w2T[c * FIN + t] = w;
            s = fmaf(w, a_src2[c], s);
            d = fmaf(w, a_dst2[c], d);
        }
        w2s[t] = s; w2d[t] = d;
    }
}

__global__ __launch_bounds__(256)
void binA_kernel(const int* __restrict__ ei, const int* __restrict__ blockhist,
                 const int* __restrict__ bucket_base,
                 int2* __restrict__ tmp, int E, int NB) {
    __shared__ int h[256];    // local cursors
    __shared__ int bb[256];   // this block's global base per bucket
    int tid = threadIdx.x;
    h[tid] = 0;
    if (tid < NB) bb[tid] = blockhist[blockIdx.x * NB + tid] + bucket_base[tid];
    __syncthreads();
    int base = blockIdx.x * EPB;
#pragma unroll
    for (int j = 0; j < EPB / 256; ++j) {
        int e = base + j * 256 + tid;
        if (e < E) {
            int s = ei[e], d = ei[E + e];
            int b = d >> 8;
            int r = atomicAdd(&h[b], 1);
            tmp[bb[b] + r] = make_int2(s, d);
        }
    }
}

// One block per bucket: sorts its bucket by node, writes csr densely and
// emits eoffs (global CSR offsets) directly.
__global__ __launch_bounds__(256)
void binB_kernel(const int2* __restrict__ tmp, const int* __restrict__ bucket_base,
                 int* __restrict__ csr, int* __restrict__ eoffs, int E, int N) {
    __shared__ int cnt[256];
    __shared__ int lds[256];
    __shared__ int cur[256];
    int b = blockIdx.x, t = threadIdx.x;
    int lo = bucket_base[b], hi = bucket_base[b + 1];
    cnt[t] = 0;
    __syncthreads();
    for (int i = lo + t; i < hi; i += 256)
        atomicAdd(&cnt[tmp[i].y & 255], 1);
    __syncthreads();
    int v = cnt[t];
    lds[t] = v;
    __syncthreads();
    for (int off = 1; off < 256; off <<= 1) {
        int u = (t >= off) ? lds[t - off] : 0;
        __syncthreads();
        lds[t] += u;
        __syncthreads();
    }
    int excl = lds[t] - v;
    int node = b * 256 + t;
    if (node < N) eoffs[node] = lo + excl;
    if (b == 0 && t == 0) eoffs[N] = E;
    cur[t] = lo + excl;
    __syncthreads();
    for (int i = lo + t; i < hi; i += 256) {
        int2 e = tmp[i];
        int p = atomicAdd(&cur[e.y & 255], 1);
        csr[p] = e.x;
    }
}

// ---------------------------------------------------------------------------
// Layer 1 GEMM via split-bf16 MFMA: h1 = x @ W1, ~fp32 accuracy.
// h1 stored bf16; alpha scalars from full fp32 accumulator.
// ---------------------------------------------------------------------------
__global__ __launch_bounds__(256)
void gemm1_mfma(const float* __restrict__ x, const float* __restrict__ W,
                const float* __restrict__ a_src, const float* __restrict__ a_dst,
                unsigned short* __restrict__ h1b, float* __restrict__ as1,
                float* __restrict__ ad1, int N) {
    __shared__ unsigned short whi[FIN * HC1];   // 32 KB, fragment-ordered
    __shared__ unsigned short wlo[FIN * HC1];   // 32 KB
    int tid = threadIdx.x;

#pragma unroll
    for (int i = 0; i < 64; ++i) {
        int idx = tid + i * 256;            // 0..16383, coalesced
        int k = idx >> 7, c = idx & 127;
        float v = W[idx];
        unsigned short hb = f2bf_rne(v);
        unsigned short lb = f2bf_rne(v - bf2f(hb));
        int kb = k >> 5, kk = k & 31;
        int g = kk >> 3, j = kk & 7;
        int ct = c >> 4, li = c & 15;
        int off = ((kb * 8 + ct) * 64 + g * 16 + li) * 8 + j;
        whi[off] = hb;
        wlo[off] = lb;
    }

    int wid = tid >> 6, lane = tid & 63;
    int li = lane & 15, g = lane >> 4;
    int rowbase = blockIdx.x * 64 + wid * 16;

    int arow = rowbase + li;
    if (arow >= N) arow = N - 1;            // clamp; invalid rows never stored
    const float* xp = x + (long)arow * FIN + g * 8;
    bf16x8 Ahi[4], Alo[4];
#pragma unroll
    for (int kb = 0; kb < 4; ++kb) {
        float4 v0 = *reinterpret_cast<const float4*>(xp + kb * 32);
        float4 v1 = *reinterpret_cast<const float4*>(xp + kb * 32 + 4);
        float vs0 = v0.x, vs1 = v0.y, vs2 = v0.z, vs3 = v0.w;
        float vs4 = v1.x, vs5 = v1.y, vs6 = v1.z, vs7 = v1.w;
        bf16x8 h8, l8;
        unsigned short hb;
        hb = f2bf_rne(vs0); h8[0] = (short)hb; l8[0] = (short)f2bf_rne(vs0 - bf2f(hb));
        hb = f2bf_rne(vs1); h8[1] = (short)hb; l8[1] = (short)f2bf_rne(vs1 - bf2f(hb));
        hb = f2bf_rne(vs2); h8[2] = (short)hb; l8[2] = (short)f2bf_rne(vs2 - bf2f(hb));
        hb = f2bf_rne(vs3); h8[3] = (short)hb; l8[3] = (short)f2bf_rne(vs3 - bf2f(hb));
        hb = f2bf_rne(vs4); h8[4] = (short)hb; l8[4] = (short)f2bf_rne(vs4 - bf2f(hb));
        hb = f2bf_rne(vs5); h8[5] = (short)hb; l8[5] = (short)f2bf_rne(vs5 - bf2f(hb));
        hb = f2bf_rne(vs6); h8[6] = (short)hb; l8[6] = (short)f2bf_rne(vs6 - bf2f(hb));
        hb = f2bf_rne(vs7); h8[7] = (short)hb; l8[7] = (short)f2bf_rne(vs7 - bf2f(hb));
        Ahi[kb] = h8; Alo[kb] = l8;
    }

    float asr[8], adr[8];
#pragma unroll
    for (int ct = 0; ct < 8; ++ct) {
        asr[ct] = a_src[ct * 16 + li];
        adr[ct] = a_dst[ct * 16 + li];
    }

    __syncthreads();

    f32x4 acc[8];
#pragma unroll
    for (int ct = 0; ct < 8; ++ct) acc[ct] = (f32x4){0.f, 0.f, 0.f, 0.f};

#pragma unroll
    for (int kb = 0; kb < 4; ++kb) {
#pragma unroll
        for (int ct = 0; ct < 8; ++ct) {
            bf16x8 bh = *reinterpret_cast<const bf16x8*>(&whi[((kb * 8 + ct) * 64 + lane) * 8]);
            bf16x8 bl = *reinterpret_cast<const bf16x8*>(&wlo[((kb * 8 + ct) * 64 + lane) * 8]);
            acc[ct] = __builtin_amdgcn_mfma_f32_16x16x32_bf16(Alo[kb], bh, acc[ct], 0, 0, 0);
            acc[ct] = __builtin_amdgcn_mfma_f32_16x16x32_bf16(Ahi[kb], bl, acc[ct], 0, 0, 0);
            acc[ct] = __builtin_amdgcn_mfma_f32_16x16x32_bf16(Ahi[kb], bh, acc[ct], 0, 0, 0);
        }
    }

    // Epilogue: store h1 (bf16) + fused per-head alpha reductions (fp32).
#pragma unroll
    for (int q = 0; q < 4; ++q) {
        int n = rowbase + g * 4 + q;
        bool valid = (n < N);
        float p0s = 0.f, p1s = 0.f, p0d = 0.f, p1d = 0.f;
#pragma unroll
        for (int ct = 0; ct < 8; ++ct) {
            float h = acc[ct][q];
            if (valid) h1b[(long)n * HC1 + ct * 16 + li] = f2bf_rne(h);
            if (ct < 4) { p0s = fmaf(h, asr[ct], p0s); p0d = fmaf(h, adr[ct], p0d); }
            else        { p1s = fmaf(h, asr[ct], p1s); p1d = fmaf(h, adr[ct], p1d); }
        }
#pragma unroll
        for (int off = 8; off >= 1; off >>= 1) {
            p0s += __shfl_xor(p0s, off, 16);
            p1s += __shfl_xor(p1s, off, 16);
            p0d += __shfl_xor(p0d, off, 16);
            p1d += __shfl_xor(p1d, off, 16);
        }
        if (valid && li == 0) {
            as1[n * 2 + 0] = p0s; as1[n * 2 + 1] = p1s;
            ad1[n * 2 + 0] = p0d; ad1[n * 2 + 1] = p1d;
        }
    }
}

// ---------------------------------------------------------------------------
// Layer 1 FUSED scores+gather+ELU+GEMM2+alpha2. 32 lanes per node,
// 8 nodes per 256-block. Epilogue v2: W2 reads from global (L1-hot, vmem
// pipe), class-fold butterfly (16 shfl), as2/ad2 via precomputed
// projections w2s/w2d (10 shfl). h2 never materialized. No LDS/barriers.
// ---------------------------------------------------------------------------
__global__ __launch_bounds__(256)
void fgather1(const int* __restrict__ eoffs, const int* __restrict__ csr,
              const float* __restrict__ as_arr, const float* __restrict__ ad_arr,
              const unsigned short* __restrict__ h1b, const float* __restrict__ b1,
              const float* __restrict__ w2T, const float* __restrict__ w2s,
              const float* __restrict__ w2d,
              float* __restrict__ zout, float* __restrict__ as2,
              float* __restrict__ ad2, int N) {
    int tid = threadIdx.x;
    int g = tid >> 5;                // 0..7 node-group in block (32-lane aligned)
    int l = tid & 31;                // lane in group: cols 4l..4l+3
    int n = blockIdx.x * 8 + g;
    if (n >= N) return;
    int head = l >> 4;
    int s0 = eoffs[n], s1 = eoffs[n + 1];

    float ad0 = ad_arr[2 * n], ad1v = ad_arr[2 * n + 1];
    float2 aself = *reinterpret_cast<const float2*>(&as_arr[2 * n]);
    float vs0 = aself.x + ad0;  vs0 = (vs0 >= 0.f) ? vs0 : NEG_SLOPE * vs0;
    float vs1 = aself.y + ad1v; vs1 = (vs1 >= 0.f) ? vs1 : NEG_SLOPE * vs1;

    // Pass A: per-head max over incoming-edge scores (self included).
    float m0 = vs0, m1 = vs1;
    for (int i = s0 + l; i < s1; i += 32) {
        float2 a = *reinterpret_cast<const float2*>(&as_arr[2 * csr[i]]);
        float v0 = a.x + ad0;  v0 = (v0 >= 0.f) ? v0 : NEG_SLOPE * v0;
        float v1 = a.y + ad1v; v1 = (v1 >= 0.f) ? v1 : NEG_SLOPE * v1;
        m0 = fmaxf(m0, v0); m1 = fmaxf(m1, v1);
    }
#pragma unroll
    for (int off = 16; off >= 1; off >>= 1) {
        m0 = fmaxf(m0, __shfl_xor(m0, off, 32));
        m1 = fmaxf(m1, __shfl_xor(m1, off, 32));
    }
    float m = head ? m1 : m0;
    float adn = head ? ad1v : ad0;

    // Pass B: gather + on-the-fly p + redundant per-lane denominator.
    float ps = __expf((head ? vs1 : vs0) - m);
    uint2 us = *reinterpret_cast<const uint2*>(&h1b[((long)n << 7) + 4 * l]);
    float4 acc;
    acc.x = bflo(us.x) * ps; acc.y = bfhi(us.x) * ps;
    acc.z = bflo(us.y) * ps; acc.w = bfhi(us.y) * ps;
    float den = ps;

    int i = s0;
    for (; i + 4 <= s1; i += 4) {
        int sa = csr[i], sb = csr[i + 1], sc = csr[i + 2], sd = csr[i + 3];
        float aa = as_arr[2 * sa + head];
        float ab = as_arr[2 * sb + head];
        float ac = as_arr[2 * sc + head];
        float ad = as_arr[2 * sd + head];
        uint2 ua = *reinterpret_cast<const uint2*>(&h1b[((long)sa << 7) + 4 * l]);
        uint2 ub = *reinterpret_cast<const uint2*>(&h1b[((long)sb << 7) + 4 * l]);
        uint2 uc = *reinterpret_cast<const uint2*>(&h1b[((long)sc << 7) + 4 * l]);
        uint2 ud = *reinterpret_cast<const uint2*>(&h1b[((long)sd << 7) + 4 * l]);
        float va = aa + adn; va = (va >= 0.f) ? va : NEG_SLOPE * va;
        float vb = ab + adn; vb = (vb >= 0.f) ? vb : NEG_SLOPE * vb;
        float vc = ac + adn; vc = (vc >= 0.f) ? vc : NEG_SLOPE * vc;
        float vd = ad + adn; vd = (vd >= 0.f) ? vd : NEG_SLOPE * vd;
        float wa = __expf(va - m);
        float wb = __expf(vb - m);
        float wc = __expf(vc - m);
        float wd = __expf(vd - m);
        den += wa + wb + wc + wd;
        acc.x = fmaf(bflo(ua.x), wa, acc.x); acc.y = fmaf(bfhi(ua.x), wa, acc.y);
        acc.z = fmaf(bflo(ua.y), wa, acc.z); acc.w = fmaf(bfhi(ua.y), wa, acc.w);
        acc.x = fmaf(bflo(ub.x), wb, acc.x); acc.y = fmaf(bfhi(ub.x), wb, acc.y);
        acc.z = fmaf(bflo(ub.y), wb, acc.z); acc.w = fmaf(bfhi(ub.y), wb, acc.w);
        acc.x = fmaf(bflo(uc.x), wc, acc.x); acc.y = fmaf(bfhi(uc.x), wc, acc.y);
        acc.z = fmaf(bflo(uc.y), wc, acc.z); acc.w = fmaf(bfhi(uc.y), wc, acc.w);
        acc.x = fmaf(bflo(ud.x), wd, acc.x); acc.y = fmaf(bfhi(ud.x), wd, acc.y);
        acc.z = fmaf(bflo(ud.y), wd, acc.z); acc.w = fmaf(bfhi(ud.y), wd, acc.w);
    }
    for (; i < s1; ++i) {
        int s = csr[i];
        float av = as_arr[2 * s + head];
        uint2 u = *reinterpret_cast<const uint2*>(&h1b[((long)s << 7) + 4 * l]);
        float v = av + adn; v = (v >= 0.f) ? v : NEG_SLOPE * v;
        float w = __expf(v - m);
        den += w;
        acc.x = fmaf(bflo(u.x), w, acc.x); acc.y = fmaf(bfhi(u.x), w, acc.y);
        acc.z = fmaf(bflo(u.y), w, acc.z); acc.w = fmaf(bfhi(u.y), w, acc.w);
    }
    float r = 1.f / (den + 1e-16f);
    int col = 4 * l;
    float4 bb = *reinterpret_cast<const float4*>(&b1[col]);
    float4 o;
    o.x = acc.x * r + bb.x; o.y = acc.y * r + bb.y;
    o.z = acc.z * r + bb.z; o.w = acc.w * r + bb.w;
    o.x = (o.x > 0.f) ? o.x : expm1f(o.x);
    o.y = (o.y > 0.f) ? o.y : expm1f(o.y);
    o.z = (o.z > 0.f) ? o.z : expm1f(o.z);
    o.w = (o.w > 0.f) ? o.w : expm1f(o.w);

    // as2/ad2 = h2 . (W2 @ a_src2), h2 . (W2 @ a_dst2)  -- 10 shfl
    float4 ws4 = *reinterpret_cast<const float4*>(&w2s[col]);
    float4 wd4 = *reinterpret_cast<const float4*>(&w2d[col]);
    float sa2 = o.x * ws4.x + o.y * ws4.y + o.z * ws4.z + o.w * ws4.w;
    float da2 = o.x * wd4.x + o.y * wd4.y + o.z * wd4.z + o.w * wd4.w;
#pragma unroll
    for (int off = 16; off >= 1; off >>= 1) {
        sa2 += __shfl_xor(sa2, off, 32);
        da2 += __shfl_xor(da2, off, 32);
    }
    if (l == 0) { as2[n] = sa2; ad2[n] = da2; }

    // z = h2 @ W2 via class-fold butterfly (16 shfl total).
    float zp[NCLS];
#pragma unroll
    for (int c = 0; c < NCLS; ++c) {
        float4 w4 = *reinterpret_cast<const float4*>(&w2T[c * FIN + col]);
        zp[c] = o.x * w4.x + o.y * w4.y + o.z * w4.z + o.w * w4.w;
    }
    int bsel = (l >> 4) & 1;
    float z8[8];
#pragma unroll
    for (int j = 0; j < 8; ++j) {
        float send = bsel ? zp[j] : zp[j + 8];
        float keep = bsel ? zp[j + 8] : zp[j];
        z8[j] = keep + __shfl_xor(send, 16, 32);
    }
    bsel = (l >> 3) & 1;
    float z4v[4];
#pragma unroll
    for (int j = 0; j < 4; ++j) {
        float send = bsel ? z8[j] : z8[j + 4];
        float keep = bsel ? z8[j + 4] : z8[j];
        z4v[j] = keep + __shfl_xor(send, 8, 32);
    }
    bsel = (l >> 2) & 1;
    float z2v[2];
#pragma unroll
    for (int j = 0; j < 2; ++j) {
        float send = bsel ? z4v[j] : z4v[j + 2];
        float keep = bsel ? z4v[j + 2] : z4v[j];
        z2v[j] = keep + __shfl_xor(send, 4, 32);
    }
    bsel = (l >> 1) & 1;
    float z1v;
    {
        float send = bsel ? z2v[0] : z2v[1];
        float keep = bsel ? z2v[1] : z2v[0];
        z1v = keep + __shfl_xor(send, 2, 32);
    }
    z1v += __shfl_xor(z1v, 1, 32);
    // lane l holds z[(l>>1)&15]; even lanes write.
    if (!(l & 1)) zout[(long)n * NCLS + ((l >> 1) & 15)] = z1v;
}

// ---------------------------------------------------------------------------
// Layer 2 FUSED scores+gather + bias + log_softmax. 16 lanes per node
// (lane = class), 16 nodes per 256-block.
// ---------------------------------------------------------------------------
__global__ __launch_bounds__(256)
void fgather2(const int* __restrict__ eoffs, const int* __restrict__ csr,
              const float* __restrict__ as2, const float* __restrict__ ad2,
              const float* __restrict__ z, const float* __restrict__ b2,
              float* __restrict__ out, int N) {
    int g = threadIdx.x >> 4;
    int l = threadIdx.x & 15;
    int n = blockIdx.x * 16 + g;
    if (n >= N) return;
    int s0 = eoffs[n], s1 = eoffs[n + 1];
    float adn = ad2[n];
    float vs = as2[n] + adn; vs = (vs >= 0.f) ? vs : NEG_SLOPE * vs;

    // Pass A: max over scores (self included).
    float m = vs;
    for (int i = s0 + l; i < s1; i += 16) {
        float v = as2[csr[i]] + adn;
        v = (v >= 0.f) ? v : NEG_SLOPE * v;
        m = fmaxf(m, v);
    }
#pragma unroll
    for (int off = 8; off >= 1; off >>= 1) m = fmaxf(m, __shfl_xor(m, off, 16));

    // Pass B: gather + on-the-fly p + redundant denominator.
    float ps = __expf(vs - m);
    float acc = ps * z[(long)n * NCLS + l];
    float den = ps;
    int i = s0;
    for (; i + 4 <= s1; i += 4) {
        int sa = csr[i], sb = csr[i + 1], sc = csr[i + 2], sd = csr[i + 3];
        float aa = as2[sa], ab = as2[sb], ac = as2[sc], ad = as2[sd];
        float za = z[sa * NCLS + l];
        float zb = z[sb * NCLS + l];
        float zc = z[sc * NCLS + l];
        float zd = z[sd * NCLS + l];
        float va = aa + adn; va = (va >= 0.f) ? va : NEG_SLOPE * va;
        float vb = ab + adn; vb = (vb >= 0.f) ? vb : NEG_SLOPE * vb;
        float vc = ac + adn; vc = (vc >= 0.f) ? vc : NEG_SLOPE * vc;
        float vd = ad + adn; vd = (vd >= 0.f) ? vd : NEG_SLOPE * vd;
        float pa = __expf(va - m);
        float pb = __expf(vb - m);
        float pc = __expf(vc - m);
        float pd = __expf(vd - m);
        den += pa + pb + pc + pd;
        acc = fmaf(za, pa, acc);
        acc = fmaf(zb, pb, acc);
        acc = fmaf(zc, pc, acc);
        acc = fmaf(zd, pd, acc);
    }
    for (; i < s1; ++i) {
        int s = csr[i];
        float v = as2[s] + adn; v = (v >= 0.f) ? v : NEG_SLOPE * v;
        float p = __expf(v - m);
        den += p;
        acc = fmaf(z[s * NCLS + l], p, acc);
    }

    float o = acc / (den + 1e-16f) + b2[l];

    float mx = o;
#pragma unroll
    for (int off = 8; off >= 1; off >>= 1) mx = fmaxf(mx, __shfl_xor(mx, off, 16));
    float ex = __expf(o - mx);
    float sum = ex;
#pragma unroll
    for (int off = 8; off >= 1; off >>= 1) sum += __shfl_xor(sum, off, 16);
    out[(long)n * NCLS + l] = o - mx - __logf(sum);
}

// ---------------------------------------------------------------------------
extern "C" void kernel_launch(void* const* d_in, const int* in_sizes, int n_in,
                              void* d_out, int out_size, void* d_ws, size_t ws_size,
                              hipStream_t stream) {
    const float* x        = (const float*)d_in[0];
    const int*   ei       = (const int*)  d_in[1];
    // d_in[2] = edge_attr (unused by reference)
    const float* W1       = (const float*)d_in[3];
    const float* att_src1 = (const float*)d_in[4];
    const float* att_dst1 = (const float*)d_in[5];
    const float* b1       = (const float*)d_in[6];
    const float* W2       = (const float*)d_in[7];
    const float* att_src2 = (const float*)d_in[8];
    const float* att_dst2 = (const float*)d_in[9];
    const float* b2       = (const float*)d_in[10];
    float* out = (float*)d_out;

    const int N = in_sizes[0] / FIN;        // 50000
    const int E = in_sizes[1] / 2;          // 800000
    const int NB = (N + 255) >> 8;          // 196 buckets
    const int EB = (E + EPB - 1) / EPB;     // 196 edge blocks (<=256)

    // Workspace layout (bytes)
    char* ws = (char*)d_ws;
    size_t off = 0;
    auto alloc = [&](size_t bytes) { char* p = ws + off; off += (bytes + 255) & ~(size_t)255; return p; };
    int*    blockhist     = (int*)  alloc((size_t)EB * NB * 4);
    int*    colsum        = (int*)  alloc((size_t)NB * 4);
    int*    bucket_base   = (int*)  alloc((size_t)(NB + 1) * 4);
    int2*   tmp           = (int2*) alloc((size_t)E * 8);
    int*    csr           = (int*)  alloc((size_t)E * 4);
    int*    eoffs         = (int*)  alloc((size_t)(N + 1) * 4);
    unsigned short* h1b   = (unsigned short*)alloc((size_t)N * HC1 * 2);  // bf16
    float*  z             = (float*) alloc((size_t)N * NCLS * 4);
    float*  as1           = (float*) alloc((size_t)N * 2 * 4);
    float*  ad1           = (float*) alloc((size_t)N * 2 * 4);
    float*  as2           = (float*) alloc((size_t)N * 4);
    float*  ad2           = (float*) alloc((size_t)N * 4);
    float*  w2T           = (float*) alloc((size_t)NCLS * FIN * 4);
    float*  w2s           = (float*) alloc((size_t)FIN * 4);
    float*  w2d           = (float*) alloc((size_t)FIN * 4);
    (void)ws_size;

    bcnt_kernel<<<EB, 256, 0, stream>>>(ei, blockhist, E, NB);
    colscan_kernel<<<NB, 256, 0, stream>>>(blockhist, colsum, EB, NB);
    bscan2_kernel<<<1, 256, 0, stream>>>(colsum, bucket_base, NB,
                                         W2, att_src2, att_dst2, w2T, w2s, w2d);
    binA_kernel<<<EB, 256, 0, stream>>>(ei, blockhist, bucket_base, tmp, E, NB);
    binB_kernel<<<NB, 256, 0, stream>>>(tmp, bucket_base, csr, eoffs, E, N);

    gemm1_mfma<<<(N + 63) / 64, 256, 0, stream>>>(
        x, W1, att_src1, att_dst1, h1b, as1, ad1, N);
    fgather1<<<(N + 7) / 8, 256, 0, stream>>>(
        eoffs, csr, as1, ad1, h1b, b1, w2T, w2s, w2d, z, as2, ad2, N);
    fgather2<<<(N + 15) / 16, 256, 0, stream>>>(eoffs, csr, as2, ad2, z, b2, out, N);
}

// Round 14
// 118.536 us; speedup vs baseline: 1.7782x; 1.0544x over previous
//
#include <hip/hip_runtime.h>
#include <math.h>

// Problem constants (match reference)
#define FIN   128
#define HC1   128   // H*C for layer 1
#define NCLS  16
#define NEG_SLOPE 0.2f

typedef __attribute__((ext_vector_type(8))) short bf16x8;
typedef __attribute__((ext_vector_type(4))) float f32x4;

__device__ __forceinline__ unsigned short f2bf_rne(float f) {
    unsigned int u = __float_as_uint(f);
    unsigned int r = u + 0x7FFFu + ((u >> 16) & 1u);
    return (unsigned short)(r >> 16);
}
__device__ __forceinline__ float bf2f(unsigned short h) {
    return __uint_as_float(((unsigned int)h) << 16);
}
__device__ __forceinline__ float bflo(unsigned int u) { return __uint_as_float(u << 16); }
__device__ __forceinline__ float bfhi(unsigned int u) { return __uint_as_float(u & 0xFFFF0000u); }

// ---------------------------------------------------------------------------
// CSR build via two-level bucket sort (bucket = dst>>8). Memset-free,
// global-atomic-free. Self-loops are NOT in the CSR (handled analytically).
// ---------------------------------------------------------------------------
#define EPB 4096   // edges per block in bcnt/binA  (EB = ceil(E/EPB) must be <=256)

__global__ __launch_bounds__(256)
void bcnt_kernel(const int* __restrict__ ei, int* __restrict__ blockhist,
                 int E, int NB) {
    __shared__ int h[256];
    int tid = threadIdx.x;
    h[tid] = 0;
    __syncthreads();
    int base = blockIdx.x * EPB;
#pragma unroll
    for (int j = 0; j < EPB / 256; ++j) {
        int e = base + j * 256 + tid;
        if (e < E) atomicAdd(&h[ei[E + e] >> 8], 1);
    }
    __syncthreads();
    if (tid < NB) blockhist[blockIdx.x * NB + tid] = h[tid];
}

// NB blocks; block t scans its COLUMN of blockhist (one element/thread).
__global__ __launch_bounds__(256)
void colscan_kernel(int* __restrict__ blockhist, int* __restrict__ colsum,
                    int EB, int NB) {
    __shared__ int lds[256];
    int t = blockIdx.x;       // bucket (column)
    int b = threadIdx.x;      // edge-block (row)
    int v = (b < EB) ? blockhist[b * NB + t] : 0;
    lds[b] = v;
    __syncthreads();
    for (int off = 1; off < 256; off <<= 1) {
        int u = (b >= off) ? lds[b - off] : 0;
        __syncthreads();
        lds[b] += u;
        __syncthreads();
    }
    if (b < EB) blockhist[b * NB + t] = lds[b] - v;   // excl offset within bucket
    if (b == 255) colsum[t] = lds[255];
}

// 1 block: exclusive scan of colsum -> bucket_base[0..NB].
// Also preps W2 transpose + alpha2 projections (independent tiny work).
__global__ __launch_bounds__(256)
void bscan2_kernel(const int* __restrict__ colsum, int* __restrict__ bucket_base,
                   int NB, const float* __restrict__ W2,
                   const float* __restrict__ a_src2, const float* __restrict__ a_dst2,
                   float* __restrict__ w2T, float* __restrict__ w2s,
                   float* __restrict__ w2d) {
    __shared__ int lds[256];
    int t = threadIdx.x;
    int v = (t < NB) ? colsum[t] : 0;
    lds[t] = v;
    __syncthreads();
    for (int off = 1; off < 256; off <<= 1) {
        int u = (t >= off) ? lds[t - off] : 0;
        __syncthreads();
        lds[t] += u;
        __syncthreads();
    }
    if (t < NB) bucket_base[t] = lds[t] - v;
    if (t == 255) bucket_base[NB] = lds[255];   // == E

    if (t < FIN) {
        float s = 0.f, d = 0.f;
#pragma unroll
        for (int c = 0; c < NCLS; ++c) {
            float w = W2[t * NCLS + c];
            w2T[c * FIN + t] = w;
            s = fmaf(w, a_src2[c], s);
            d = fmaf(w, a_dst2[c], d);
        }
        w2s[t] = s; w2d[t] = d;
    }
}

__global__ __launch_bounds__(256)
void binA_kernel(const int* __restrict__ ei, const int* __restrict__ blockhist,
                 const int* __restrict__ bucket_base,
                 int2* __restrict__ tmp, int E, int NB) {
    __shared__ int h[256];    // local cursors
    __shared__ int bb[256];   // this block's global base per bucket
    int tid = threadIdx.x;
    h[tid] = 0;
    if (tid < NB) bb[tid] = blockhist[blockIdx.x * NB + tid] + bucket_base[tid];
    __syncthreads();
    int base = blockIdx.x * EPB;
#pragma unroll
    for (int j = 0; j < EPB / 256; ++j) {
        int e = base + j * 256 + tid;
        if (e < E) {
            int s = ei[e], d = ei[E + e];
            int b = d >> 8;
            int r = atomicAdd(&h[b], 1);
            tmp[bb[b] + r] = make_int2(s, d);
        }
    }
}

// One block per bucket: sorts its bucket by node, writes csr densely and
// emits eoffs (global CSR offsets) directly.
__global__ __launch_bounds__(256)
void binB_kernel(const int2* __restrict__ tmp, const int* __restrict__ bucket_base,
                 int* __restrict__ csr, int* __restrict__ eoffs, int E, int N) {
    __shared__ int cnt[256];
    __shared__ int lds[256];
    __shared__ int cur[256];
    int b = blockIdx.x, t = threadIdx.x;
    int lo = bucket_base[b], hi = bucket_base[b + 1];
    cnt[t] = 0;
    __syncthreads();
    for (int i = lo + t; i < hi; i += 256)
        atomicAdd(&cnt[tmp[i].y & 255], 1);
    __syncthreads();
    int v = cnt[t];
    lds[t] = v;
    __syncthreads();
    for (int off = 1; off < 256; off <<= 1) {
        int u = (t >= off) ? lds[t - off] : 0;
        __syncthreads();
        lds[t] += u;
        __syncthreads();
    }
    int excl = lds[t] - v;
    int node = b * 256 + t;
    if (node < N) eoffs[node] = lo + excl;
    if (b == 0 && t == 0) eoffs[N] = E;
    cur[t] = lo + excl;
    __syncthreads();
    for (int i = lo + t; i < hi; i += 256) {
        int2 e = tmp[i];
        int p = atomicAdd(&cur[e.y & 255], 1);
        csr[p] = e.x;
    }
}

// ---------------------------------------------------------------------------
// Layer 1 GEMM via split-bf16 MFMA: h1 = x @ W1, ~fp32 accuracy.
// h1 stored bf16; alpha scalars from full fp32 accumulator.
// ---------------------------------------------------------------------------
__global__ __launch_bounds__(256)
void gemm1_mfma(const float* __restrict__ x, const float* __restrict__ W,
                const float* __restrict__ a_src, const float* __restrict__ a_dst,
                unsigned short* __restrict__ h1b, float* __restrict__ as1,
                float* __restrict__ ad1, int N) {
    __shared__ unsigned short whi[FIN * HC1];   // 32 KB, fragment-ordered
    __shared__ unsigned short wlo[FIN * HC1];   // 32 KB
    int tid = threadIdx.x;

#pragma unroll
    for (int i = 0; i < 64; ++i) {
        int idx = tid + i * 256;            // 0..16383, coalesced
        int k = idx >> 7, c = idx & 127;
        float v = W[idx];
        unsigned short hb = f2bf_rne(v);
        unsigned short lb = f2bf_rne(v - bf2f(hb));
        int kb = k >> 5, kk = k & 31;
        int g = kk >> 3, j = kk & 7;
        int ct = c >> 4, li = c & 15;
        int off = ((kb * 8 + ct) * 64 + g * 16 + li) * 8 + j;
        whi[off] = hb;
        wlo[off] = lb;
    }

    int wid = tid >> 6, lane = tid & 63;
    int li = lane & 15, g = lane >> 4;
    int rowbase = blockIdx.x * 64 + wid * 16;

    int arow = rowbase + li;
    if (arow >= N) arow = N - 1;            // clamp; invalid rows never stored
    const float* xp = x + (long)arow * FIN + g * 8;
    bf16x8 Ahi[4], Alo[4];
#pragma unroll
    for (int kb = 0; kb < 4; ++kb) {
        float4 v0 = *reinterpret_cast<const float4*>(xp + kb * 32);
        float4 v1 = *reinterpret_cast<const float4*>(xp + kb * 32 + 4);
        float vs0 = v0.x, vs1 = v0.y, vs2 = v0.z, vs3 = v0.w;
        float vs4 = v1.x, vs5 = v1.y, vs6 = v1.z, vs7 = v1.w;
        bf16x8 h8, l8;
        unsigned short hb;
        hb = f2bf_rne(vs0); h8[0] = (short)hb; l8[0] = (short)f2bf_rne(vs0 - bf2f(hb));
        hb = f2bf_rne(vs1); h8[1] = (short)hb; l8[1] = (short)f2bf_rne(vs1 - bf2f(hb));
        hb = f2bf_rne(vs2); h8[2] = (short)hb; l8[2] = (short)f2bf_rne(vs2 - bf2f(hb));
        hb = f2bf_rne(vs3); h8[3] = (short)hb; l8[3] = (short)f2bf_rne(vs3 - bf2f(hb));
        hb = f2bf_rne(vs4); h8[4] = (short)hb; l8[4] = (short)f2bf_rne(vs4 - bf2f(hb));
        hb = f2bf_rne(vs5); h8[5] = (short)hb; l8[5] = (short)f2bf_rne(vs5 - bf2f(hb));
        hb = f2bf_rne(vs6); h8[6] = (short)hb; l8[6] = (short)f2bf_rne(vs6 - bf2f(hb));
        hb = f2bf_rne(vs7); h8[7] = (short)hb; l8[7] = (short)f2bf_rne(vs7 - bf2f(hb));
        Ahi[kb] = h8; Alo[kb] = l8;
    }

    float asr[8], adr[8];
#pragma unroll
    for (int ct = 0; ct < 8; ++ct) {
        asr[ct] = a_src[ct * 16 + li];
        adr[ct] = a_dst[ct * 16 + li];
    }

    __syncthreads();

    f32x4 acc[8];
#pragma unroll
    for (int ct = 0; ct < 8; ++ct) acc[ct] = (f32x4){0.f, 0.f, 0.f, 0.f};

#pragma unroll
    for (int kb = 0; kb < 4; ++kb) {
#pragma unroll
        for (int ct = 0; ct < 8; ++ct) {
            bf16x8 bh = *reinterpret_cast<const bf16x8*>(&whi[((kb * 8 + ct) * 64 + lane) * 8]);
            bf16x8 bl = *reinterpret_cast<const bf16x8*>(&wlo[((kb * 8 + ct) * 64 + lane) * 8]);
            acc[ct] = __builtin_amdgcn_mfma_f32_16x16x32_bf16(Alo[kb], bh, acc[ct], 0, 0, 0);
            acc[ct] = __builtin_amdgcn_mfma_f32_16x16x32_bf16(Ahi[kb], bl, acc[ct], 0, 0, 0);
            acc[ct] = __builtin_amdgcn_mfma_f32_16x16x32_bf16(Ahi[kb], bh, acc[ct], 0, 0, 0);
        }
    }

    // Epilogue: store h1 (bf16) + fused per-head alpha reductions (fp32).
#pragma unroll
    for (int q = 0; q < 4; ++q) {
        int n = rowbase + g * 4 + q;
        bool valid = (n < N);
        float p0s = 0.f, p1s = 0.f, p0d = 0.f, p1d = 0.f;
#pragma unroll
        for (int ct = 0; ct < 8; ++ct) {
            float h = acc[ct][q];
            if (valid) h1b[(long)n * HC1 + ct * 16 + li] = f2bf_rne(h);
            if (ct < 4) { p0s = fmaf(h, asr[ct], p0s); p0d = fmaf(h, adr[ct], p0d); }
            else        { p1s = fmaf(h, asr[ct], p1s); p1d = fmaf(h, adr[ct], p1d); }
        }
#pragma unroll
        for (int off = 8; off >= 1; off >>= 1) {
            p0s += __shfl_xor(p0s, off, 16);
            p1s += __shfl_xor(p1s, off, 16);
            p0d += __shfl_xor(p0d, off, 16);
            p1d += __shfl_xor(p1d, off, 16);
        }
        if (valid && li == 0) {
            as1[n * 2 + 0] = p0s; as1[n * 2 + 1] = p1s;
            ad1[n * 2 + 0] = p0d; ad1[n * 2 + 1] = p1d;
        }
    }
}

// ---------------------------------------------------------------------------
// Layer 1 FUSED gather+softmax+ELU+GEMM2+alpha2. 32 lanes per node,
// 8 nodes per 256-block. SINGLE edge pass: softmax computed without
// max-subtraction (scores bounded ~|6|; exp in [1e-3,4e2], fp32-safe;
// mathematically identical ratios). Epilogue: W2 global (L1-hot),
// class-fold butterfly (16 shfl), as2/ad2 via projections. No LDS/barriers.
// ---------------------------------------------------------------------------
__global__ __launch_bounds__(256)
void fgather1(const int* __restrict__ eoffs, const int* __restrict__ csr,
              const float* __restrict__ as_arr, const float* __restrict__ ad_arr,
              const unsigned short* __restrict__ h1b, const float* __restrict__ b1,
              const float* __restrict__ w2T, const float* __restrict__ w2s,
              const float* __restrict__ w2d,
              float* __restrict__ zout, float* __restrict__ as2,
              float* __restrict__ ad2, int N) {
    int tid = threadIdx.x;
    int g = tid >> 5;                // 0..7 node-group in block (32-lane aligned)
    int l = tid & 31;                // lane in group: cols 4l..4l+3
    int n = blockIdx.x * 8 + g;
    if (n >= N) return;
    int head = l >> 4;
    int s0 = eoffs[n], s1 = eoffs[n + 1];

    float ad0 = ad_arr[2 * n], ad1v = ad_arr[2 * n + 1];
    float2 aself = *reinterpret_cast<const float2*>(&as_arr[2 * n]);
    float vs0 = aself.x + ad0;  vs0 = (vs0 >= 0.f) ? vs0 : NEG_SLOPE * vs0;
    float vs1 = aself.y + ad1v; vs1 = (vs1 >= 0.f) ? vs1 : NEG_SLOPE * vs1;
    float adn = head ? ad1v : ad0;

    // Single pass: gather + on-the-fly p=exp(v) + redundant denominator.
    float ps = __expf(head ? vs1 : vs0);
    uint2 us = *reinterpret_cast<const uint2*>(&h1b[((long)n << 7) + 4 * l]);
    float4 acc;
    acc.x = bflo(us.x) * ps; acc.y = bfhi(us.x) * ps;
    acc.z = bflo(us.y) * ps; acc.w = bfhi(us.y) * ps;
    float den = ps;

    int i = s0;
    for (; i + 4 <= s1; i += 4) {
        int sa = csr[i], sb = csr[i + 1], sc = csr[i + 2], sd = csr[i + 3];
        float aa = as_arr[2 * sa + head];
        float ab = as_arr[2 * sb + head];
        float ac = as_arr[2 * sc + head];
        float ad = as_arr[2 * sd + head];
        uint2 ua = *reinterpret_cast<const uint2*>(&h1b[((long)sa << 7) + 4 * l]);
        uint2 ub = *reinterpret_cast<const uint2*>(&h1b[((long)sb << 7) + 4 * l]);
        uint2 uc = *reinterpret_cast<const uint2*>(&h1b[((long)sc << 7) + 4 * l]);
        uint2 ud = *reinterpret_cast<const uint2*>(&h1b[((long)sd << 7) + 4 * l]);
        float va = aa + adn; va = (va >= 0.f) ? va : NEG_SLOPE * va;
        float vb = ab + adn; vb = (vb >= 0.f) ? vb : NEG_SLOPE * vb;
        float vc = ac + adn; vc = (vc >= 0.f) ? vc : NEG_SLOPE * vc;
        float vd = ad + adn; vd = (vd >= 0.f) ? vd : NEG_SLOPE * vd;
        float wa = __expf(va);
        float wb = __expf(vb);
        float wc = __expf(vc);
        float wd = __expf(vd);
        den += wa + wb + wc + wd;
        acc.x = fmaf(bflo(ua.x), wa, acc.x); acc.y = fmaf(bfhi(ua.x), wa, acc.y);
        acc.z = fmaf(bflo(ua.y), wa, acc.z); acc.w = fmaf(bfhi(ua.y), wa, acc.w);
        acc.x = fmaf(bflo(ub.x), wb, acc.x); acc.y = fmaf(bfhi(ub.x), wb, acc.y);
        acc.z = fmaf(bflo(ub.y), wb, acc.z); acc.w = fmaf(bfhi(ub.y), wb, acc.w);
        acc.x = fmaf(bflo(uc.x), wc, acc.x); acc.y = fmaf(bfhi(uc.x), wc, acc.y);
        acc.z = fmaf(bflo(uc.y), wc, acc.z); acc.w = fmaf(bfhi(uc.y), wc, acc.w);
        acc.x = fmaf(bflo(ud.x), wd, acc.x); acc.y = fmaf(bfhi(ud.x), wd, acc.y);
        acc.z = fmaf(bflo(ud.y), wd, acc.z); acc.w = fmaf(bfhi(ud.y), wd, acc.w);
    }
    for (; i < s1; ++i) {
        int s = csr[i];
        float av = as_arr[2 * s + head];
        uint2 u = *reinterpret_cast<const uint2*>(&h1b[((long)s << 7) + 4 * l]);
        float v = av + adn; v = (v >= 0.f) ? v : NEG_SLOPE * v;
        float w = __expf(v);
        den += w;
        acc.x = fmaf(bflo(u.x), w, acc.x); acc.y = fmaf(bfhi(u.x), w, acc.y);
        acc.z = fmaf(bflo(u.y), w, acc.z); acc.w = fmaf(bfhi(u.y), w, acc.w);
    }
    float r = 1.f / (den + 1e-16f);
    int col = 4 * l;
    float4 bb = *reinterpret_cast<const float4*>(&b1[col]);
    float4 o;
    o.x = acc.x * r + bb.x; o.y = acc.y * r + bb.y;
    o.z = acc.z * r + bb.z; o.w = acc.w * r + bb.w;
    o.x = (o.x > 0.f) ? o.x : expm1f(o.x);
    o.y = (o.y > 0.f) ? o.y : expm1f(o.y);
    o.z = (o.z > 0.f) ? o.z : expm1f(o.z);
    o.w = (o.w > 0.f) ? o.w : expm1f(o.w);

    // as2/ad2 = h2 . (W2 @ a_src2), h2 . (W2 @ a_dst2)  -- 10 shfl
    float4 ws4 = *reinterpret_cast<const float4*>(&w2s[col]);
    float4 wd4 = *reinterpret_cast<const float4*>(&w2d[col]);
    float sa2 = o.x * ws4.x + o.y * ws4.y + o.z * ws4.z + o.w * ws4.w;
    float da2 = o.x * wd4.x + o.y * wd4.y + o.z * wd4.z + o.w * wd4.w;
#pragma unroll
    for (int off = 16; off >= 1; off >>= 1) {
        sa2 += __shfl_xor(sa2, off, 32);
        da2 += __shfl_xor(da2, off, 32);
    }
    if (l == 0) { as2[n] = sa2; ad2[n] = da2; }

    // z = h2 @ W2 via class-fold butterfly (16 shfl total).
    float zp[NCLS];
#pragma unroll
    for (int c = 0; c < NCLS; ++c) {
        float4 w4 = *reinterpret_cast<const float4*>(&w2T[c * FIN + col]);
        zp[c] = o.x * w4.x + o.y * w4.y + o.z * w4.z + o.w * w4.w;
    }
    int bsel = (l >> 4) & 1;
    float z8[8];
#pragma unroll
    for (int j = 0; j < 8; ++j) {
        float send = bsel ? zp[j] : zp[j + 8];
        float keep = bsel ? zp[j + 8] : zp[j];
        z8[j] = keep + __shfl_xor(send, 16, 32);
    }
    bsel = (l >> 3) & 1;
    float z4v[4];
#pragma unroll
    for (int j = 0; j < 4; ++j) {
        float send = bsel ? z8[j] : z8[j + 4];
        float keep = bsel ? z8[j + 4] : z8[j];
        z4v[j] = keep + __shfl_xor(send, 8, 32);
    }
    bsel = (l >> 2) & 1;
    float z2v[2];
#pragma unroll
    for (int j = 0; j < 2; ++j) {
        float send = bsel ? z4v[j] : z4v[j + 2];
        float keep = bsel ? z4v[j + 2] : z4v[j];
        z2v[j] = keep + __shfl_xor(send, 4, 32);
    }
    bsel = (l >> 1) & 1;
    float z1v;
    {
        float send = bsel ? z2v[0] : z2v[1];
        float keep = bsel ? z2v[1] : z2v[0];
        z1v = keep + __shfl_xor(send, 2, 32);
    }
    z1v += __shfl_xor(z1v, 1, 32);
    // lane l holds z[(l>>1)&15]; even lanes write.
    if (!(l & 1)) zout[(long)n * NCLS + ((l >> 1) & 15)] = z1v;
}

// ---------------------------------------------------------------------------
// Layer 2 FUSED gather+softmax + bias + log_softmax. 16 lanes per node
// (lane = class), 16 nodes per 256-block. Single pass, no max-subtraction.
// ---------------------------------------------------------------------------
__global__ __launch_bounds__(256)
void fgather2(const int* __restrict__ eoffs, const int* __restrict__ csr,
              const float* __restrict__ as2, const float* __restrict__ ad2,
              const float* __restrict__ z, const float* __restrict__ b2,
              float* __restrict__ out, int N) {
    int g = threadIdx.x >> 4;
    int l = threadIdx.x & 15;
    int n = blockIdx.x * 16 + g;
    if (n >= N) return;
    int s0 = eoffs[n], s1 = eoffs[n + 1];
    float adn = ad2[n];
    float vs = as2[n] + adn; vs = (vs >= 0.f) ? vs : NEG_SLOPE * vs;

    // Single pass: gather + on-the-fly p=exp(v) + redundant denominator.
    float ps = __expf(vs);
    float acc = ps * z[(long)n * NCLS + l];
    float den = ps;
    int i = s0;
    for (; i + 4 <= s1; i += 4) {
        int sa = csr[i], sb = csr[i + 1], sc = csr[i + 2], sd = csr[i + 3];
        float aa = as2[sa], ab = as2[sb], ac = as2[sc], ad = as2[sd];
        float za = z[sa * NCLS + l];
        float zb = z[sb * NCLS + l];
        float zc = z[sc * NCLS + l];
        float zd = z[sd * NCLS + l];
        float va = aa + adn; va = (va >= 0.f) ? va : NEG_SLOPE * va;
        float vb = ab + adn; vb = (vb >= 0.f) ? vb : NEG_SLOPE * vb;
        float vc = ac + adn; vc = (vc >= 0.f) ? vc : NEG_SLOPE * vc;
        float vd = ad + adn; vd = (vd >= 0.f) ? vd : NEG_SLOPE * vd;
        float pa = __expf(va);
        float pb = __expf(vb);
        float pc = __expf(vc);
        float pd = __expf(vd);
        den += pa + pb + pc + pd;
        acc = fmaf(za, pa, acc);
        acc = fmaf(zb, pb, acc);
        acc = fmaf(zc, pc, acc);
        acc = fmaf(zd, pd, acc);
    }
    for (; i < s1; ++i) {
        int s = csr[i];
        float v = as2[s] + adn; v = (v >= 0.f) ? v : NEG_SLOPE * v;
        float p = __expf(v);
        den += p;
        acc = fmaf(z[s * NCLS + l], p, acc);
    }

    float o = acc / (den + 1e-16f) + b2[l];

    float mx = o;
#pragma unroll
    for (int off = 8; off >= 1; off >>= 1) mx = fmaxf(mx, __shfl_xor(mx, off, 16));
    float ex = __expf(o - mx);
    float sum = ex;
#pragma unroll
    for (int off = 8; off >= 1; off >>= 1) sum += __shfl_xor(sum, off, 16);
    out[(long)n * NCLS + l] = o - mx - __logf(sum);
}

// ---------------------------------------------------------------------------
extern "C" void kernel_launch(void* const* d_in, const int* in_sizes, int n_in,
                              void* d_out, int out_size, void* d_ws, size_t ws_size,
                              hipStream_t stream) {
    const float* x        = (const float*)d_in[0];
    const int*   ei       = (const int*)  d_in[1];
    // d_in[2] = edge_attr (unused by reference)
    const float* W1       = (const float*)d_in[3];
    const float* att_src1 = (const float*)d_in[4];
    const float* att_dst1 = (const float*)d_in[5];
    const float* b1       = (const float*)d_in[6];
    const float* W2       = (const float*)d_in[7];
    const float* att_src2 = (const float*)d_in[8];
    const float* att_dst2 = (const float*)d_in[9];
    const float* b2       = (const float*)d_in[10];
    float* out = (float*)d_out;

    const int N = in_sizes[0] / FIN;        // 50000
    const int E = in_sizes[1] / 2;          // 800000
    const int NB = (N + 255) >> 8;          // 196 buckets
    const int EB = (E + EPB - 1) / EPB;     // 196 edge blocks (<=256)

    // Workspace layout (bytes)
    char* ws = (char*)d_ws;
    size_t off = 0;
    auto alloc = [&](size_t bytes) { char* p = ws + off; off += (bytes + 255) & ~(size_t)255; return p; };
    int*    blockhist     = (int*)  alloc((size_t)EB * NB * 4);
    int*    colsum        = (int*)  alloc((size_t)NB * 4);
    int*    bucket_base   = (int*)  alloc((size_t)(NB + 1) * 4);
    int2*   tmp           = (int2*) alloc((size_t)E * 8);
    int*    csr           = (int*)  alloc((size_t)E * 4);
    int*    eoffs         = (int*)  alloc((size_t)(N + 1) * 4);
    unsigned short* h1b   = (unsigned short*)alloc((size_t)N * HC1 * 2);  // bf16
    float*  z             = (float*) alloc((size_t)N * NCLS * 4);
    float*  as1           = (float*) alloc((size_t)N * 2 * 4);
    float*  ad1           = (float*) alloc((size_t)N * 2 * 4);
    float*  as2           = (float*) alloc((size_t)N * 4);
    float*  ad2           = (float*) alloc((size_t)N * 4);
    float*  w2T           = (float*) alloc((size_t)NCLS * FIN * 4);
    float*  w2s           = (float*) alloc((size_t)FIN * 4);
    float*  w2d           = (float*) alloc((size_t)FIN * 4);
    (void)ws_size;

    bcnt_kernel<<<EB, 256, 0, stream>>>(ei, blockhist, E, NB);
    colscan_kernel<<<NB, 256, 0, stream>>>(blockhist, colsum, EB, NB);
    bscan2_kernel<<<1, 256, 0, stream>>>(colsum, bucket_base, NB,
                                         W2, att_src2, att_dst2, w2T, w2s, w2d);
    binA_kernel<<<EB, 256, 0, stream>>>(ei, blockhist, bucket_base, tmp, E, NB);
    binB_kernel<<<NB, 256, 0, stream>>>(tmp, bucket_base, csr, eoffs, E, N);

    gemm1_mfma<<<(N + 63) / 64, 256, 0, stream>>>(
        x, W1, att_src1, att_dst1, h1b, as1, ad1, N);
    fgather1<<<(N + 7) / 8, 256, 0, stream>>>(
        eoffs, csr, as1, ad1, h1b, b1, w2T, w2s, w2d, z, as2, ad2, N);
    fgather2<<<(N + 15) / 16, 256, 0, stream>>>(eoffs, csr, as2, ad2, z, b2, out, N);
}

// Round 15
// 108.768 us; speedup vs baseline: 1.9379x; 1.0898x over previous
//
#include <hip/hip_runtime.h>
#include <math.h>

// Problem constants (match reference)
#define FIN   128
#define HC1   128   // H*C for layer 1
#define NCLS  16
#define NEG_SLOPE 0.2f

typedef __attribute__((ext_vector_type(8))) short bf16x8;
typedef __attribute__((ext_vector_type(4))) float f32x4;

__device__ __forceinline__ unsigned short f2bf_rne(float f) {
    unsigned int u = __float_as_uint(f);
    unsigned int r = u + 0x7FFFu + ((u >> 16) & 1u);
    return (unsigned short)(r >> 16);
}
__device__ __forceinline__ float bf2f(unsigned short h) {
    return __uint_as_float(((unsigned int)h) << 16);
}
__device__ __forceinline__ float bflo(unsigned int u) { return __uint_as_float(u << 16); }
__device__ __forceinline__ float bfhi(unsigned int u) { return __uint_as_float(u & 0xFFFF0000u); }

#define EPB 4096   // edges per block in bcnt/binA  (EB = ceil(E/EPB) must be <=256)

// ---------------------------------------------------------------------------
// gemm1 body (split-bf16 MFMA, h1=x@W1 -> bf16, fused alpha1 reductions).
// Called from the fused CSR kernels with an explicit block id and a 64 KB
// shared scratch (whi/wlo fragment-ordered W1).
// ---------------------------------------------------------------------------
__device__ __forceinline__
void gemm1_body(const float* __restrict__ x, const float* __restrict__ W,
                const float* __restrict__ a_src, const float* __restrict__ a_dst,
                unsigned short* __restrict__ h1b, float* __restrict__ as1,
                float* __restrict__ ad1, int N, int bid, float4* smem) {
    unsigned short* whi = (unsigned short*)smem;          // 32 KB
    unsigned short* wlo = whi + FIN * HC1;                // 32 KB
    int tid = threadIdx.x;

#pragma unroll
    for (int i = 0; i < 64; ++i) {
        int idx = tid + i * 256;            // 0..16383, coalesced
        int k = idx >> 7, c = idx & 127;
        float v = W[idx];
        unsigned short hb = f2bf_rne(v);
        unsigned short lb = f2bf_rne(v - bf2f(hb));
        int kb = k >> 5, kk = k & 31;
        int g = kk >> 3, j = kk & 7;
        int ct = c >> 4, li = c & 15;
        int off = ((kb * 8 + ct) * 64 + g * 16 + li) * 8 + j;
        whi[off] = hb;
        wlo[off] = lb;
    }

    int wid = tid >> 6, lane = tid & 63;
    int li = lane & 15, g = lane >> 4;
    int rowbase = bid * 64 + wid * 16;

    int arow = rowbase + li;
    if (arow >= N) arow = N - 1;            // clamp; invalid rows never stored
    const float* xp = x + (long)arow * FIN + g * 8;
    bf16x8 Ahi[4], Alo[4];
#pragma unroll
    for (int kb = 0; kb < 4; ++kb) {
        float4 v0 = *reinterpret_cast<const float4*>(xp + kb * 32);
        float4 v1 = *reinterpret_cast<const float4*>(xp + kb * 32 + 4);
        float vs0 = v0.x, vs1 = v0.y, vs2 = v0.z, vs3 = v0.w;
        float vs4 = v1.x, vs5 = v1.y, vs6 = v1.z, vs7 = v1.w;
        bf16x8 h8, l8;
        unsigned short hb;
        hb = f2bf_rne(vs0); h8[0] = (short)hb; l8[0] = (short)f2bf_rne(vs0 - bf2f(hb));
        hb = f2bf_rne(vs1); h8[1] = (short)hb; l8[1] = (short)f2bf_rne(vs1 - bf2f(hb));
        hb = f2bf_rne(vs2); h8[2] = (short)hb; l8[2] = (short)f2bf_rne(vs2 - bf2f(hb));
        hb = f2bf_rne(vs3); h8[3] = (short)hb; l8[3] = (short)f2bf_rne(vs3 - bf2f(hb));
        hb = f2bf_rne(vs4); h8[4] = (short)hb; l8[4] = (short)f2bf_rne(vs4 - bf2f(hb));
        hb = f2bf_rne(vs5); h8[5] = (short)hb; l8[5] = (short)f2bf_rne(vs5 - bf2f(hb));
        hb = f2bf_rne(vs6); h8[6] = (short)hb; l8[6] = (short)f2bf_rne(vs6 - bf2f(hb));
        hb = f2bf_rne(vs7); h8[7] = (short)hb; l8[7] = (short)f2bf_rne(vs7 - bf2f(hb));
        Ahi[kb] = h8; Alo[kb] = l8;
    }

    float asr[8], adr[8];
#pragma unroll
    for (int ct = 0; ct < 8; ++ct) {
        asr[ct] = a_src[ct * 16 + li];
        adr[ct] = a_dst[ct * 16 + li];
    }

    __syncthreads();

    f32x4 acc[8];
#pragma unroll
    for (int ct = 0; ct < 8; ++ct) acc[ct] = (f32x4){0.f, 0.f, 0.f, 0.f};

#pragma unroll
    for (int kb = 0; kb < 4; ++kb) {
#pragma unroll
        for (int ct = 0; ct < 8; ++ct) {
            bf16x8 bh = *reinterpret_cast<const bf16x8*>(&whi[((kb * 8 + ct) * 64 + lane) * 8]);
            bf16x8 bl = *reinterpret_cast<const bf16x8*>(&wlo[((kb * 8 + ct) * 64 + lane) * 8]);
            acc[ct] = __builtin_amdgcn_mfma_f32_16x16x32_bf16(Alo[kb], bh, acc[ct], 0, 0, 0);
            acc[ct] = __builtin_amdgcn_mfma_f32_16x16x32_bf16(Ahi[kb], bl, acc[ct], 0, 0, 0);
            acc[ct] = __builtin_amdgcn_mfma_f32_16x16x32_bf16(Ahi[kb], bh, acc[ct], 0, 0, 0);
        }
    }

#pragma unroll
    for (int q = 0; q < 4; ++q) {
        int n = rowbase + g * 4 + q;
        bool valid = (n < N);
        float p0s = 0.f, p1s = 0.f, p0d = 0.f, p1d = 0.f;
#pragma unroll
        for (int ct = 0; ct < 8; ++ct) {
            float h = acc[ct][q];
            if (valid) h1b[(long)n * HC1 + ct * 16 + li] = f2bf_rne(h);
            if (ct < 4) { p0s = fmaf(h, asr[ct], p0s); p0d = fmaf(h, adr[ct], p0d); }
            else        { p1s = fmaf(h, asr[ct], p1s); p1d = fmaf(h, adr[ct], p1d); }
        }
#pragma unroll
        for (int off = 8; off >= 1; off >>= 1) {
            p0s += __shfl_xor(p0s, off, 16);
            p1s += __shfl_xor(p1s, off, 16);
            p0d += __shfl_xor(p0d, off, 16);
            p1d += __shfl_xor(p1d, off, 16);
        }
        if (valid && li == 0) {
            as1[n * 2 + 0] = p0s; as1[n * 2 + 1] = p1s;
            ad1[n * 2 + 0] = p0d; ad1[n * 2 + 1] = p1d;
        }
    }
}

// ---------------------------------------------------------------------------
// FUSED CSR-build kernels: first nb_csr blocks do the CSR phase, remaining
// blocks run a gemm1 slice (gemm1 is independent of the CSR chain; all
// slices complete before fgather1). Branch is per-block -> barriers legal.
// ---------------------------------------------------------------------------
__global__ __launch_bounds__(256)
void f_bcnt(const int* __restrict__ ei, int* __restrict__ blockhist, int E, int NB,
            const float* __restrict__ x, const float* __restrict__ W1,
            const float* __restrict__ a_src, const float* __restrict__ a_dst,
            unsigned short* __restrict__ h1b, float* __restrict__ as1,
            float* __restrict__ ad1, int N, int nb_csr, int gemm_base) {
    __shared__ float4 smem[4096];   // 64 KB shared scratch
    int tid = threadIdx.x;
    if ((int)blockIdx.x >= nb_csr) {
        gemm1_body(x, W1, a_src, a_dst, h1b, as1, ad1, N,
                   gemm_base + blockIdx.x - nb_csr, smem);
        return;
    }
    int* h = (int*)smem;
    h[tid] = 0;
    __syncthreads();
    int base = blockIdx.x * EPB;
#pragma unroll
    for (int j = 0; j < EPB / 256; ++j) {
        int e = base + j * 256 + tid;
        if (e < E) atomicAdd(&h[ei[E + e] >> 8], 1);
    }
    __syncthreads();
    if (tid < NB) blockhist[blockIdx.x * NB + tid] = h[tid];
}

__global__ __launch_bounds__(256)
void f_colscan(int* __restrict__ blockhist, int* __restrict__ colsum, int EB, int NB,
               const float* __restrict__ x, const float* __restrict__ W1,
               const float* __restrict__ a_src, const float* __restrict__ a_dst,
               unsigned short* __restrict__ h1b, float* __restrict__ as1,
               float* __restrict__ ad1, int N, int nb_csr, int gemm_base) {
    __shared__ float4 smem[4096];
    int b = threadIdx.x;
    if ((int)blockIdx.x >= nb_csr) {
        gemm1_body(x, W1, a_src, a_dst, h1b, as1, ad1, N,
                   gemm_base + blockIdx.x - nb_csr, smem);
        return;
    }
    int* lds = (int*)smem;
    int t = blockIdx.x;       // bucket (column)
    int v = (b < EB) ? blockhist[b * NB + t] : 0;
    lds[b] = v;
    __syncthreads();
    for (int off = 1; off < 256; off <<= 1) {
        int u = (b >= off) ? lds[b - off] : 0;
        __syncthreads();
        lds[b] += u;
        __syncthreads();
    }
    if (b < EB) blockhist[b * NB + t] = lds[b] - v;   // excl offset within bucket
    if (b == 255) colsum[t] = lds[255];
}

// 1 block: exclusive scan of colsum -> bucket_base; + W2 prep.
__global__ __launch_bounds__(256)
void bscan2_kernel(const int* __restrict__ colsum, int* __restrict__ bucket_base,
                   int NB, const float* __restrict__ W2,
                   const float* __restrict__ a_src2, const float* __restrict__ a_dst2,
                   float* __restrict__ w2T, float* __restrict__ w2s,
                   float* __restrict__ w2d) {
    __shared__ int lds[256];
    int t = threadIdx.x;
    int v = (t < NB) ? colsum[t] : 0;
    lds[t] = v;
    __syncthreads();
    for (int off = 1; off < 256; off <<= 1) {
        int u = (t >= off) ? lds[t - off] : 0;
        __syncthreads();
        lds[t] += u;
        __syncthreads();
    }
    if (t < NB) bucket_base[t] = lds[t] - v;
    if (t == 255) bucket_base[NB] = lds[255];   // == E

    if (t < FIN) {
        float s = 0.f, d = 0.f;
#pragma unroll
        for (int c = 0; c < NCLS; ++c) {
            float w = W2[t * NCLS + c];
            w2T[c * FIN + t] = w;
            s = fmaf(w, a_src2[c], s);
            d = fmaf(w, a_dst2[c], d);
        }
        w2s[t] = s; w2d[t] = d;
    }
}

__global__ __launch_bounds__(256)
void f_binA(const int* __restrict__ ei, const int* __restrict__ blockhist,
            const int* __restrict__ bucket_base, int2* __restrict__ tmp,
            int E, int NB,
            const float* __restrict__ x, const float* __restrict__ W1,
            const float* __restrict__ a_src, const float* __restrict__ a_dst,
            unsigned short* __restrict__ h1b, float* __restrict__ as1,
            float* __restrict__ ad1, int N, int nb_csr, int gemm_base) {
    __shared__ float4 smem[4096];
    int tid = threadIdx.x;
    if ((int)blockIdx.x >= nb_csr) {
        gemm1_body(x, W1, a_src, a_dst, h1b, as1, ad1, N,
                   gemm_base + blockIdx.x - nb_csr, smem);
        return;
    }
    int* h  = (int*)smem;        // local cursors [256]
    int* bb = h + 256;           // global base per bucket [256]
    h[tid] = 0;
    if (tid < NB) bb[tid] = blockhist[blockIdx.x * NB + tid] + bucket_base[tid];
    __syncthreads();
    int base = blockIdx.x * EPB;
#pragma unroll
    for (int j = 0; j < EPB / 256; ++j) {
        int e = base + j * 256 + tid;
        if (e < E) {
            int s = ei[e], d = ei[E + e];
            int b = d >> 8;
            int r = atomicAdd(&h[b], 1);
            tmp[bb[b] + r] = make_int2(s, d);
        }
    }
}

__global__ __launch_bounds__(256)
void f_binB(const int2* __restrict__ tmp, const int* __restrict__ bucket_base,
            int* __restrict__ csr, int* __restrict__ eoffs, int E, int N,
            const float* __restrict__ x, const float* __restrict__ W1,
            const float* __restrict__ a_src, const float* __restrict__ a_dst,
            unsigned short* __restrict__ h1b, float* __restrict__ as1,
            float* __restrict__ ad1, int nb_csr, int gemm_base) {
    __shared__ float4 smem[4096];
    int t = threadIdx.x;
    if ((int)blockIdx.x >= nb_csr) {
        gemm1_body(x, W1, a_src, a_dst, h1b, as1, ad1, N,
                   gemm_base + blockIdx.x - nb_csr, smem);
        return;
    }
    int* cnt = (int*)smem;       // [256]
    int* lds = cnt + 256;        // [256]
    int* cur = cnt + 512;        // [256]
    int b = blockIdx.x;
    int lo = bucket_base[b], hi = bucket_base[b + 1];
    cnt[t] = 0;
    __syncthreads();
    for (int i = lo + t; i < hi; i += 256)
        atomicAdd(&cnt[tmp[i].y & 255], 1);
    __syncthreads();
    int v = cnt[t];
    lds[t] = v;
    __syncthreads();
    for (int off = 1; off < 256; off <<= 1) {
        int u = (t >= off) ? lds[t - off] : 0;
        __syncthreads();
        lds[t] += u;
        __syncthreads();
    }
    int excl = lds[t] - v;
    int node = b * 256 + t;
    if (node < N) eoffs[node] = lo + excl;
    if (b == 0 && t == 0) eoffs[N] = E;
    cur[t] = lo + excl;
    __syncthreads();
    for (int i = lo + t; i < hi; i += 256) {
        int2 e = tmp[i];
        int p = atomicAdd(&cur[e.y & 255], 1);
        csr[p] = e.x;
    }
}

// ---------------------------------------------------------------------------
// Layer 1 FUSED gather+softmax+ELU+GEMM2+alpha2 (single edge pass, no
// max-subtraction; class-fold butterfly epilogue). Unchanged from R14.
// ---------------------------------------------------------------------------
__global__ __launch_bounds__(256)
void fgather1(const int* __restrict__ eoffs, const int* __restrict__ csr,
              const float* __restrict__ as_arr, const float* __restrict__ ad_arr,
              const unsigned short* __restrict__ h1b, const float* __restrict__ b1,
              const float* __restrict__ w2T, const float* __restrict__ w2s,
              const float* __restrict__ w2d,
              float* __restrict__ zout, float* __restrict__ as2,
              float* __restrict__ ad2, int N) {
    int tid = threadIdx.x;
    int g = tid >> 5;                // 0..7 node-group in block (32-lane aligned)
    int l = tid & 31;                // lane in group: cols 4l..4l+3
    int n = blockIdx.x * 8 + g;
    if (n >= N) return;
    int head = l >> 4;
    int s0 = eoffs[n], s1 = eoffs[n + 1];

    float ad0 = ad_arr[2 * n], ad1v = ad_arr[2 * n + 1];
    float2 aself = *reinterpret_cast<const float2*>(&as_arr[2 * n]);
    float vs0 = aself.x + ad0;  vs0 = (vs0 >= 0.f) ? vs0 : NEG_SLOPE * vs0;
    float vs1 = aself.y + ad1v; vs1 = (vs1 >= 0.f) ? vs1 : NEG_SLOPE * vs1;
    float adn = head ? ad1v : ad0;

    float ps = __expf(head ? vs1 : vs0);
    uint2 us = *reinterpret_cast<const uint2*>(&h1b[((long)n << 7) + 4 * l]);
    float4 acc;
    acc.x = bflo(us.x) * ps; acc.y = bfhi(us.x) * ps;
    acc.z = bflo(us.y) * ps; acc.w = bfhi(us.y) * ps;
    float den = ps;

    int i = s0;
    for (; i + 4 <= s1; i += 4) {
        int sa = csr[i], sb = csr[i + 1], sc = csr[i + 2], sd = csr[i + 3];
        float aa = as_arr[2 * sa + head];
        float ab = as_arr[2 * sb + head];
        float ac = as_arr[2 * sc + head];
        float ad = as_arr[2 * sd + head];
        uint2 ua = *reinterpret_cast<const uint2*>(&h1b[((long)sa << 7) + 4 * l]);
        uint2 ub = *reinterpret_cast<const uint2*>(&h1b[((long)sb << 7) + 4 * l]);
        uint2 uc = *reinterpret_cast<const uint2*>(&h1b[((long)sc << 7) + 4 * l]);
        uint2 ud = *reinterpret_cast<const uint2*>(&h1b[((long)sd << 7) + 4 * l]);
        float va = aa + adn; va = (va >= 0.f) ? va : NEG_SLOPE * va;
        float vb = ab + adn; vb = (vb >= 0.f) ? vb : NEG_SLOPE * vb;
        float vc = ac + adn; vc = (vc >= 0.f) ? vc : NEG_SLOPE * vc;
        float vd = ad + adn; vd = (vd >= 0.f) ? vd : NEG_SLOPE * vd;
        float wa = __expf(va);
        float wb = __expf(vb);
        float wc = __expf(vc);
        float wd = __expf(vd);
        den += wa + wb + wc + wd;
        acc.x = fmaf(bflo(ua.x), wa, acc.x); acc.y = fmaf(bfhi(ua.x), wa, acc.y);
        acc.z = fmaf(bflo(ua.y), wa, acc.z); acc.w = fmaf(bfhi(ua.y), wa, acc.w);
        acc.x = fmaf(bflo(ub.x), wb, acc.x); acc.y = fmaf(bfhi(ub.x), wb, acc.y);
        acc.z = fmaf(bflo(ub.y), wb, acc.z); acc.w = fmaf(bfhi(ub.y), wb, acc.w);
        acc.x = fmaf(bflo(uc.x), wc, acc.x); acc.y = fmaf(bfhi(uc.x), wc, acc.y);
        acc.z = fmaf(bflo(uc.y), wc, acc.z); acc.w = fmaf(bfhi(uc.y), wc, acc.w);
        acc.x = fmaf(bflo(ud.x), wd, acc.x); acc.y = fmaf(bfhi(ud.x), wd, acc.y);
        acc.z = fmaf(bflo(ud.y), wd, acc.z); acc.w = fmaf(bfhi(ud.y), wd, acc.w);
    }
    for (; i < s1; ++i) {
        int s = csr[i];
        float av = as_arr[2 * s + head];
        uint2 u = *reinterpret_cast<const uint2*>(&h1b[((long)s << 7) + 4 * l]);
        float v = av + adn; v = (v >= 0.f) ? v : NEG_SLOPE * v;
        float w = __expf(v);
        den += w;
        acc.x = fmaf(bflo(u.x), w, acc.x); acc.y = fmaf(bfhi(u.x), w, acc.y);
        acc.z = fmaf(bflo(u.y), w, acc.z); acc.w = fmaf(bfhi(u.y), w, acc.w);
    }
    float r = 1.f / (den + 1e-16f);
    int col = 4 * l;
    float4 bb = *reinterpret_cast<const float4*>(&b1[col]);
    float4 o;
    o.x = acc.x * r + bb.x; o.y = acc.y * r + bb.y;
    o.z = acc.z * r + bb.z; o.w = acc.w * r + bb.w;
    o.x = (o.x > 0.f) ? o.x : expm1f(o.x);
    o.y = (o.y > 0.f) ? o.y : expm1f(o.y);
    o.z = (o.z > 0.f) ? o.z : expm1f(o.z);
    o.w = (o.w > 0.f) ? o.w : expm1f(o.w);

    // as2/ad2 = h2 . (W2 @ a_src2), h2 . (W2 @ a_dst2)  -- 10 shfl
    float4 ws4 = *reinterpret_cast<const float4*>(&w2s[col]);
    float4 wd4 = *reinterpret_cast<const float4*>(&w2d[col]);
    float sa2 = o.x * ws4.x + o.y * ws4.y + o.z * ws4.z + o.w * ws4.w;
    float da2 = o.x * wd4.x + o.y * wd4.y + o.z * wd4.z + o.w * wd4.w;
#pragma unroll
    for (int off = 16; off >= 1; off >>= 1) {
        sa2 += __shfl_xor(sa2, off, 32);
        da2 += __shfl_xor(da2, off, 32);
    }
    if (l == 0) { as2[n] = sa2; ad2[n] = da2; }

    // z = h2 @ W2 via class-fold butterfly (16 shfl total).
    float zp[NCLS];
#pragma unroll
    for (int c = 0; c < NCLS; ++c) {
        float4 w4 = *reinterpret_cast<const float4*>(&w2T[c * FIN + col]);
        zp[c] = o.x * w4.x + o.y * w4.y + o.z * w4.z + o.w * w4.w;
    }
    int bsel = (l >> 4) & 1;
    float z8[8];
#pragma unroll
    for (int j = 0; j < 8; ++j) {
        float send = bsel ? zp[j] : zp[j + 8];
        float keep = bsel ? zp[j + 8] : zp[j];
        z8[j] = keep + __shfl_xor(send, 16, 32);
    }
    bsel = (l >> 3) & 1;
    float z4v[4];
#pragma unroll
    for (int j = 0; j < 4; ++j) {
        float send = bsel ? z8[j] : z8[j + 4];
        float keep = bsel ? z8[j + 4] : z8[j];
        z4v[j] = keep + __shfl_xor(send, 8, 32);
    }
    bsel = (l >> 2) & 1;
    float z2v[2];
#pragma unroll
    for (int j = 0; j < 2; ++j) {
        float send = bsel ? z4v[j] : z4v[j + 2];
        float keep = bsel ? z4v[j + 2] : z4v[j];
        z2v[j] = keep + __shfl_xor(send, 4, 32);
    }
    bsel = (l >> 1) & 1;
    float z1v;
    {
        float send = bsel ? z2v[0] : z2v[1];
        float keep = bsel ? z2v[1] : z2v[0];
        z1v = keep + __shfl_xor(send, 2, 32);
    }
    z1v += __shfl_xor(z1v, 1, 32);
    if (!(l & 1)) zout[(long)n * NCLS + ((l >> 1) & 15)] = z1v;
}

// ---------------------------------------------------------------------------
// Layer 2 FUSED gather+softmax + bias + log_softmax (unchanged from R14).
// ---------------------------------------------------------------------------
__global__ __launch_bounds__(256)
void fgather2(const int* __restrict__ eoffs, const int* __restrict__ csr,
              const float* __restrict__ as2, const float* __restrict__ ad2,
              const float* __restrict__ z, const float* __restrict__ b2,
              float* __restrict__ out, int N) {
    int g = threadIdx.x >> 4;
    int l = threadIdx.x & 15;
    int n = blockIdx.x * 16 + g;
    if (n >= N) return;
    int s0 = eoffs[n], s1 = eoffs[n + 1];
    float adn = ad2[n];
    float vs = as2[n] + adn; vs = (vs >= 0.f) ? vs : NEG_SLOPE * vs;

    float ps = __expf(vs);
    float acc = ps * z[(long)n * NCLS + l];
    float den = ps;
    int i = s0;
    for (; i + 4 <= s1; i += 4) {
        int sa = csr[i], sb = csr[i + 1], sc = csr[i + 2], sd = csr[i + 3];
        float aa = as2[sa], ab = as2[sb], ac = as2[sc], ad = as2[sd];
        float za = z[sa * NCLS + l];
        float zb = z[sb * NCLS + l];
        float zc = z[sc * NCLS + l];
        float zd = z[sd * NCLS + l];
        float va = aa + adn; va = (va >= 0.f) ? va : NEG_SLOPE * va;
        float vb = ab + adn; vb = (vb >= 0.f) ? vb : NEG_SLOPE * vb;
        float vc = ac + adn; vc = (vc >= 0.f) ? vc : NEG_SLOPE * vc;
        float vd = ad + adn; vd = (vd >= 0.f) ? vd : NEG_SLOPE * vd;
        float pa = __expf(va);
        float pb = __expf(vb);
        float pc = __expf(vc);
        float pd = __expf(vd);
        den += pa + pb + pc + pd;
        acc = fmaf(za, pa, acc);
        acc = fmaf(zb, pb, acc);
        acc = fmaf(zc, pc, acc);
        acc = fmaf(zd, pd, acc);
    }
    for (; i < s1; ++i) {
        int s = csr[i];
        float v = as2[s] + adn; v = (v >= 0.f) ? v : NEG_SLOPE * v;
        float p = __expf(v);
        den += p;
        acc = fmaf(z[s * NCLS + l], p, acc);
    }

    float o = acc / (den + 1e-16f) + b2[l];

    float mx = o;
#pragma unroll
    for (int off = 8; off >= 1; off >>= 1) mx = fmaxf(mx, __shfl_xor(mx, off, 16));
    float ex = __expf(o - mx);
    float sum = ex;
#pragma unroll
    for (int off = 8; off >= 1; off >>= 1) sum += __shfl_xor(sum, off, 16);
    out[(long)n * NCLS + l] = o - mx - __logf(sum);
}

// ---------------------------------------------------------------------------
extern "C" void kernel_launch(void* const* d_in, const int* in_sizes, int n_in,
                              void* d_out, int out_size, void* d_ws, size_t ws_size,
                              hipStream_t stream) {
    const float* x        = (const float*)d_in[0];
    const int*   ei       = (const int*)  d_in[1];
    // d_in[2] = edge_attr (unused by reference)
    const float* W1       = (const float*)d_in[3];
    const float* att_src1 = (const float*)d_in[4];
    const float* att_dst1 = (const float*)d_in[5];
    const float* b1       = (const float*)d_in[6];
    const float* W2       = (const float*)d_in[7];
    const float* att_src2 = (const float*)d_in[8];
    const float* att_dst2 = (const float*)d_in[9];
    const float* b2       = (const float*)d_in[10];
    float* out = (float*)d_out;

    const int N = in_sizes[0] / FIN;        // 50000
    const int E = in_sizes[1] / 2;          // 800000
    const int NB = (N + 255) >> 8;          // 196 buckets
    const int EB = (E + EPB - 1) / EPB;     // 196 edge blocks (<=256)
    const int GB = (N + 63) / 64;           // 782 gemm1 blocks

    // gemm1 block slices fused into the 4 parallel CSR kernels
    int q = GB / 4, rr = GB % 4;
    int g0 = q + (rr > 0 ? 1 : 0);
    int g1 = q + (rr > 1 ? 1 : 0);
    int g2 = q + (rr > 2 ? 1 : 0);
    int g3 = q;
    int b0 = 0, b1o = g0, b2o = g0 + g1, b3o = g0 + g1 + g2;

    // Workspace layout (bytes)
    char* ws = (char*)d_ws;
    size_t off = 0;
    auto alloc = [&](size_t bytes) { char* p = ws + off; off += (bytes + 255) & ~(size_t)255; return p; };
    int*    blockhist     = (int*)  alloc((size_t)EB * NB * 4);
    int*    colsum        = (int*)  alloc((size_t)NB * 4);
    int*    bucket_base   = (int*)  alloc((size_t)(NB + 1) * 4);
    int2*   tmp           = (int2*) alloc((size_t)E * 8);
    int*    csr           = (int*)  alloc((size_t)E * 4);
    int*    eoffs         = (int*)  alloc((size_t)(N + 1) * 4);
    unsigned short* h1b   = (unsigned short*)alloc((size_t)N * HC1 * 2);  // bf16
    float*  z             = (float*) alloc((size_t)N * NCLS * 4);
    float*  as1           = (float*) alloc((size_t)N * 2 * 4);
    float*  ad1           = (float*) alloc((size_t)N * 2 * 4);
    float*  as2           = (float*) alloc((size_t)N * 4);
    float*  ad2           = (float*) alloc((size_t)N * 4);
    float*  w2T           = (float*) alloc((size_t)NCLS * FIN * 4);
    float*  w2s           = (float*) alloc((size_t)FIN * 4);
    float*  w2d           = (float*) alloc((size_t)FIN * 4);
    (void)ws_size;

    f_bcnt<<<EB + g0, 256, 0, stream>>>(ei, blockhist, E, NB,
        x, W1, att_src1, att_dst1, h1b, as1, ad1, N, EB, b0);
    f_colscan<<<NB + g1, 256, 0, stream>>>(blockhist, colsum, EB, NB,
        x, W1, att_src1, att_dst1, h1b, as1, ad1, N, NB, b1o);
    bscan2_kernel<<<1, 256, 0, stream>>>(colsum, bucket_base, NB,
                                         W2, att_src2, att_dst2, w2T, w2s, w2d);
    f_binA<<<EB + g2, 256, 0, stream>>>(ei, blockhist, bucket_base, tmp, E, NB,
        x, W1, att_src1, att_dst1, h1b, as1, ad1, N, EB, b2o);
    f_binB<<<NB + g3, 256, 0, stream>>>(tmp, bucket_base, csr, eoffs, E, N,
        x, W1, att_src1, att_dst1, h1b, as1, ad1, NB, b3o);

    fgather1<<<(N + 7) / 8, 256, 0, stream>>>(
        eoffs, csr, as1, ad1, h1b, b1, w2T, w2s, w2d, z, as2, ad2, N);
    fgather2<<<(N + 15) / 16, 256, 0, stream>>>(eoffs, csr, as2, ad2, z, b2, out, N);
}